// Round 9
// baseline (182.550 us; speedup 1.0000x reference)
//
#include <hip/hip_runtime.h>
#include <hip/hip_bf16.h>

// MoE MLP top-1 + shared expert. T=2048 H=768 I=2048 E=8, f32 in/out.
// R9: wconv = gll16-f32 staging (issue-early) + counted vmcnt(4/6/2) + raw
//     s_barriers (wait-late) + 32KB LDS (5 blocks/CU) + nt-adjacent chunk
//     groups (2KB read granule). Router fused. Stages = R7 (validated).
// Chunk = 128 n x 32 k bf16 (4096 u16 = 8KB), in-chunk addr:
//   ((n>>4)&7)*512 + ((k>>3)&3)*128 + (n&15)*8 + (k&7)
// gll16 copies chunks linearly; MFMA fragment reads are linear-in-lane.

#define TT 2048
#define HH 768
#define II 2048
#define NE 8
#define RSLOTS 3072   // routed padded slots (24 tiles of 128)
#define WBLK 2880     // wconv blocks: 1728 gate/up (4 chunks) + 1152 down (3)

typedef unsigned short u16;
typedef unsigned int u32;
typedef short s16x8 __attribute__((ext_vector_type(8)));
typedef u16 u16x8 __attribute__((ext_vector_type(8)));
typedef float f32x4 __attribute__((ext_vector_type(4)));

__device__ __forceinline__ u16 f2bf(float f) {  // f32 -> bf16 RNE
  u32 u = __builtin_bit_cast(u32, f);
  return (u16)((u + 0x7FFFu + ((u >> 16) & 1u)) >> 16);
}

typedef __attribute__((address_space(3))) u32 lds_u32;
typedef const __attribute__((address_space(1))) u32 glb_u32;
__device__ __forceinline__ void gll16(const void* g, void* l) {
  // global src per-lane; LDS dest wave-uniform base + lane*16 (linear)
  __builtin_amdgcn_global_load_lds((glb_u32*)g,
                                   (lds_u32*)(u32)(unsigned long long)l, 16, 0, 0);
}

// stage one [32k x 128n] f32 chunk (rows stride N) into linear LDS [32][128]
__device__ __forceinline__ void wc_issue(const float* src, int N, float* ldsbuf,
                                         int wid, int lane) {
  const int rr = lane >> 5;            // row within pair
  const int c4 = (lane & 31) * 4;      // 16B per lane
#pragma unroll
  for (int q = 0; q < 4; ++q) {
    const int row = wid * 8 + q * 2;
    gll16(src + (size_t)(row + rr) * N + c4, ldsbuf + (size_t)row * 128);
  }
}

// NCH chunks, double-buffered, counted vmcnt, 2 raw barriers/iter.
template <int NCH>
__device__ __forceinline__ void wconv_body(const float* const* srcj, u16* const* dstj,
                                           int N, float (*fbuf)[32 * 128], int t,
                                           int wid, int lane) {
  wc_issue(srcj[0], N, fbuf[0], wid, lane);
  wc_issue(srcj[1], N, fbuf[1], wid, lane);
#pragma unroll
  for (int j = 0; j < NCH; ++j) {
    if (j == 0) {
      asm volatile("s_waitcnt vmcnt(4)" ::: "memory");
    } else if (j < NCH - 1) {
      asm volatile("s_waitcnt vmcnt(6)" ::: "memory");
    } else {
      asm volatile("s_waitcnt vmcnt(2)" ::: "memory");
    }
    __builtin_amdgcn_s_barrier();
    // transpose-convert chunk j from fbuf[j&1] (4-way LDS read conflicts, ok)
    u16* dst = dstj[j];
    const float* fb = fbuf[j & 1];
#pragma unroll
    for (int r = 0; r < 2; ++r) {
      const int o = t + r * 256;  // 0..511
      const int fr = o & 15, fq = (o >> 4) & 3, nq = o >> 6;
      const float* lp = &fb[(fq * 8) * 128 + nq * 16 + fr];
      u16x8 w;
#pragma unroll
      for (int jj = 0; jj < 8; ++jj) w[jj] = f2bf(lp[jj * 128]);
      *reinterpret_cast<u16x8*>(&dst[o * 8]) = w;
    }
    __builtin_amdgcn_s_barrier();
    if (j + 2 < NCH) wc_issue(srcj[j + 2], N, fbuf[j & 1], wid, lane);
  }
}

// ---------------- fused wconv + router ----------------
// gu blocks b<1728: em=b/96 (e=em>>1, mat=em&1), r=b%96, ntg=r/24, kc=r%24;
//   chunks j=0..3 at nt=ntg*4+j (adjacent 512B src windows -> 2KB granule).
// down blocks: b2=b-1728: e=b2/128, r=b2%128, ntg=r/64, kc=r%64; j=0..2,
//   nt=ntg*3+j. expert 8 = shared.
__global__ __launch_bounds__(256) void wconv_router_kernel(
    const float* __restrict__ gate_w, const float* __restrict__ up_w,
    const float* __restrict__ down_w, const float* __restrict__ sh_gate,
    const float* __restrict__ sh_up, const float* __restrict__ sh_down,
    u16* __restrict__ Wgt, u16* __restrict__ Wut, u16* __restrict__ Wdt,
    const float* __restrict__ x, const float* __restrict__ rw,
    float* __restrict__ score, int* __restrict__ list, int* __restrict__ cnt,
    float* __restrict__ probsum) {
  __shared__ float fbuf[2][32 * 128];  // 32 KB
  const int t = threadIdx.x, wid = t >> 6, lane = t & 63;

  if (blockIdx.x >= WBLK) {
    // ---- router: one wave per token ----
    const int tok = (int)(((blockIdx.x - WBLK) * 256 + t) >> 6);
    if (tok >= TT) return;
    double acc[NE];
#pragma unroll
    for (int e = 0; e < NE; ++e) acc[e] = 0.0;
    const float* xr = x + (size_t)tok * HH;
    for (int h = lane; h < HH; h += 64) {
      const double xv = (double)xr[h];
#pragma unroll
      for (int e = 0; e < NE; ++e) acc[e] += xv * (double)rw[h * NE + e];
    }
#pragma unroll
    for (int off = 32; off > 0; off >>= 1) {
#pragma unroll
      for (int e = 0; e < NE; ++e) acc[e] += __shfl_xor(acc[e], off);
    }
    if (lane == 0) {
      int best = 0;
#pragma unroll
      for (int e = 1; e < NE; ++e)
        if (acc[e] > acc[best]) best = e;  // strict > == first-max (jnp.argmax)
      const float sc = 1.0f / (1.0f + __expf((float)(-acc[best])));
      score[tok] = sc;
      const int pos = atomicAdd(&cnt[best], 1);
      list[best * TT + pos] = tok;
      atomicAdd(&probsum[best], sc);
    }
    return;
  }

  const int b = blockIdx.x;
  if (b < 1728) {
    const int em = b / 96, r = b % 96, ntg = r / 24, kc = r % 24;
    const int e = em >> 1;
    const float* base = (em & 1) ? (e < 8 ? up_w + (size_t)e * HH * II : sh_up)
                                 : (e < 8 ? gate_w + (size_t)e * HH * II : sh_gate);
    u16* wt = (em & 1) ? Wut : Wgt;
    const float* srcj[4];
    u16* dstj[4];
#pragma unroll
    for (int j = 0; j < 4; ++j) {
      const int nt = ntg * 4 + j;
      srcj[j] = base + (size_t)(kc * 32) * II + nt * 128;
      dstj[j] = wt + ((size_t)(e * 16 + nt) * 24 + kc) * 4096;
    }
    wconv_body<4>(srcj, dstj, II, fbuf, t, wid, lane);
  } else {
    const int b2 = b - 1728;
    const int e = b2 / 128, r = b2 % 128, ntg = r / 64, kc = r % 64;
    const float* base = (e < 8) ? down_w + (size_t)e * II * HH : sh_down;
    const float* srcj[3];
    u16* dstj[3];
#pragma unroll
    for (int j = 0; j < 3; ++j) {
      const int nt = ntg * 3 + j;
      srcj[j] = base + (size_t)(kc * 32) * HH + nt * 128;
      dstj[j] = Wdt + ((size_t)(e * 6 + nt) * 64 + kc) * 4096;
    }
    wconv_body<3>(srcj, dstj, HH, fbuf, t, wid, lane);
  }
}

// ---------------- plan: padded segments + tile->expert + loss ----------------
__global__ void plan_kernel(const int* __restrict__ cnt, const float* __restrict__ probsum,
                            int* __restrict__ meta, float* __restrict__ out) {
  if (threadIdx.x == 0) {
    int S = 0;
    for (int e = 0; e < NE; ++e) {
      meta[e] = S;
      const int pad = (cnt[e] + 127) & ~127;
      for (int t = S >> 7; t < (S + pad) >> 7; ++t) meta[16 + t] = e;
      S += pad;
    }
    meta[8] = S;
    for (int t = S >> 7; t < 24; ++t) meta[16 + t] = 0;
    float s = 0.0f;
    for (int e = 0; e < NE; ++e) s += (float)cnt[e] * probsum[e];
    out[(size_t)TT * HH] = s * (0.001f * (float)NE / ((float)TT * (float)TT));
  }
}

// ---------------- gather: x -> tiled bf16 Xc (+tokmap) ----------------
__global__ __launch_bounds__(256) void gather_kernel(
    const float* __restrict__ x, const float* __restrict__ score,
    const int* __restrict__ list, const int* __restrict__ cnt,
    const int* __restrict__ meta, u16* __restrict__ Xc, int* __restrict__ tokmap) {
  const int task = blockIdx.x * 4 + (threadIdx.x >> 6);
  const int lane = threadIdx.x & 63;
  const int pb = task / 24;  // 16-row block, 0..319
  const int c = task % 24;   // k chunk
  const int fq = lane >> 4, fr = lane & 15;
  const int p = pb * 16 + fr;
  int tok;
  float sc;
  if (p >= RSLOTS) {
    tok = p - RSLOTS;
    sc = 1.0f;
  } else {
    const int e = meta[16 + (p >> 7)];
    const int idx = p - meta[e];
    tok = (idx >= 0 && idx < cnt[e]) ? list[e * TT + idx] : -1;
    sc = (tok >= 0) ? score[tok] : 0.0f;
  }
  u16x8 w = {0, 0, 0, 0, 0, 0, 0, 0};
  if (tok >= 0) {
    const float* xp = x + (size_t)tok * HH + c * 32 + fq * 8;
    const f32x4 a = *reinterpret_cast<const f32x4*>(xp);
    const f32x4 b = *reinterpret_cast<const f32x4*>(xp + 4);
#pragma unroll
    for (int j = 0; j < 4; ++j) {
      w[j] = f2bf(a[j] * sc);
      w[j + 4] = f2bf(b[j] * sc);
    }
  }
  *reinterpret_cast<u16x8*>(&Xc[((size_t)(pb >> 3) * 24 + c) * 4096 + (pb & 7) * 512 +
                                lane * 8]) = w;
  if (c == 0 && fq == 0) tokmap[p] = tok;
}

// ---------------- stage A: P = silu(Xc Wg) * (Xc Wu) ----------------
// grid (16 nt, 40 mty): mty<24 routed (early-exit past Rp), >=24 shared (e=8).
__global__ __launch_bounds__(256, 2) void stageA_kernel(
    const u16* __restrict__ Xc, const int* __restrict__ meta,
    const u16* __restrict__ Wgt, const u16* __restrict__ Wut, u16* __restrict__ P) {
  const int mty = blockIdx.y, nt = blockIdx.x;
  int e;
  if (mty < 24) {
    if (mty * 128 >= meta[8]) return;
    e = meta[16 + mty];
  } else {
    e = 8;
  }
  const u16* wg = Wgt + (size_t)(e * 16 + nt) * 24 * 4096;
  const u16* wu = Wut + (size_t)(e * 16 + nt) * 24 * 4096;
  const u16* xa = Xc + (size_t)mty * 24 * 4096;

  __shared__ u16 As[2][4096], Bgs[2][4096], Bus[2][4096];

  const int tid = threadIdx.x, lane = tid & 63, wid = tid >> 6;
  const int fr = lane & 15, fq = lane >> 4;
  const int wm4 = (wid >> 1) * 4;  // row 16-block base
  const int wn4 = (wid & 1) * 4;   // col 16-block base
  const int wn = (wid & 1) * 64;
  const int ncol = nt * 128;
  const int so = wid * 1024 + lane * 8;  // gll global src offset (u16)
  const int sl = wid * 1024;             // gll LDS dst offset (u16), wave-uniform

  f32x4 accg[4][4], accu[4][4];
#pragma unroll
  for (int i = 0; i < 4; ++i)
#pragma unroll
    for (int j = 0; j < 4; ++j) {
      accg[i][j] = f32x4{0.f, 0.f, 0.f, 0.f};
      accu[i][j] = f32x4{0.f, 0.f, 0.f, 0.f};
    }

  // full chunk = 4096 u16; 4 waves x 2 gll16 x 512 u16 each
#define STAGE(c, buf)                                               \
  {                                                                 \
    gll16(xa + (size_t)(c) * 4096 + so, &As[buf][sl]);              \
    gll16(xa + (size_t)(c) * 4096 + so + 512, &As[buf][sl + 512]);  \
    gll16(wg + (size_t)(c) * 4096 + so, &Bgs[buf][sl]);             \
    gll16(wg + (size_t)(c) * 4096 + so + 512, &Bgs[buf][sl + 512]); \
    gll16(wu + (size_t)(c) * 4096 + so, &Bus[buf][sl]);             \
    gll16(wu + (size_t)(c) * 4096 + so + 512, &Bus[buf][sl + 512]); \
  }

  STAGE(0, 0)
  __syncthreads();
  int cur = 0;
  for (int c = 0; c < 24; ++c) {
    if (c < 23) STAGE(c + 1, cur ^ 1)
    s16x8 af[4], bg[4], bu[4];
#pragma unroll
    for (int i = 0; i < 4; ++i) {
      af[i] = *reinterpret_cast<const s16x8*>(&As[cur][(wm4 + i) * 512 + fq * 128 + fr * 8]);
      bg[i] = *reinterpret_cast<const s16x8*>(&Bgs[cur][(wn4 + i) * 512 + fq * 128 + fr * 8]);
      bu[i] = *reinterpret_cast<const s16x8*>(&Bus[cur][(wn4 + i) * 512 + fq * 128 + fr * 8]);
    }
#pragma unroll
    for (int j = 0; j < 4; ++j)
#pragma unroll
      for (int i = 0; i < 4; ++i) {
        accg[i][j] = __builtin_amdgcn_mfma_f32_16x16x32_bf16(af[i], bg[j], accg[i][j], 0, 0, 0);
        accu[i][j] = __builtin_amdgcn_mfma_f32_16x16x32_bf16(af[i], bu[j], accu[i][j], 0, 0, 0);
      }
    __syncthreads();
    cur ^= 1;
  }
#undef STAGE

  // epilogue: silu(g)*u -> P tiled bf16 (C/D: row=fq*4+reg, col=fr)
#pragma unroll
  for (int i = 0; i < 4; ++i)
#pragma unroll
    for (int cc = 0; cc < 4; ++cc) {
      const int rlo = fq * 4 + cc;  // row & 15 within 16-block (wm4+i)
#pragma unroll
      for (int j = 0; j < 4; ++j) {
        const int k = ncol + wn + j * 16 + fr;  // global i-col
        const float gv = accg[i][j][cc];
        const float val = (gv / (1.0f + __expf(-gv))) * accu[i][j][cc];
        P[((size_t)mty * 64 + (k >> 5)) * 4096 + (size_t)(wm4 + i) * 512 +
          ((k >> 3) & 3) * 128 + rlo * 8 + (k & 7)] = f2bf(val);
      }
    }
}

// ---------------- stage B: out += P Wd (atomicAdd, out pre-zeroed) ----------------
// grid (6 nt, 40 mty); each out element gets one shared + at most one routed add.
__global__ __launch_bounds__(256, 2) void stageB_kernel(
    const u16* __restrict__ P, const int* __restrict__ meta,
    const int* __restrict__ tokmap, const u16* __restrict__ Wdt,
    float* __restrict__ out) {
  const int mty = blockIdx.y, nt = blockIdx.x;
  int e;
  if (mty < 24) {
    if (mty * 128 >= meta[8]) return;
    e = meta[16 + mty];
  } else {
    e = 8;
  }
  const u16* wd = Wdt + (size_t)(e * 6 + nt) * 64 * 4096;
  const u16* pa = P + (size_t)mty * 64 * 4096;

  __shared__ u16 As[2][4096], Bs[2][4096];

  const int tid = threadIdx.x, lane = tid & 63, wid = tid >> 6;
  const int fr = lane & 15, fq = lane >> 4;
  const int wm4 = (wid >> 1) * 4;
  const int wn4 = (wid & 1) * 4;
  const int wm = (wid >> 1) * 64;
  const int wn = (wid & 1) * 64;
  const int ncol = nt * 128;
  const int so = wid * 1024 + lane * 8;
  const int sl = wid * 1024;

  f32x4 acc[4][4];
#pragma unroll
  for (int i = 0; i < 4; ++i)
#pragma unroll
    for (int j = 0; j < 4; ++j) acc[i][j] = f32x4{0.f, 0.f, 0.f, 0.f};

#define STAGEB(c, buf)                                              \
  {                                                                 \
    gll16(pa + (size_t)(c) * 4096 + so, &As[buf][sl]);              \
    gll16(pa + (size_t)(c) * 4096 + so + 512, &As[buf][sl + 512]);  \
    gll16(wd + (size_t)(c) * 4096 + so, &Bs[buf][sl]);              \
    gll16(wd + (size_t)(c) * 4096 + so + 512, &Bs[buf][sl + 512]);  \
  }

  STAGEB(0, 0)
  __syncthreads();
  int cur = 0;
  for (int c = 0; c < 64; ++c) {
    if (c < 63) STAGEB(c + 1, cur ^ 1)
    s16x8 af[4], bf[4];
#pragma unroll
    for (int i = 0; i < 4; ++i) {
      af[i] = *reinterpret_cast<const s16x8*>(&As[cur][(wm4 + i) * 512 + fq * 128 + fr * 8]);
      bf[i] = *reinterpret_cast<const s16x8*>(&Bs[cur][(wn4 + i) * 512 + fq * 128 + fr * 8]);
    }
#pragma unroll
    for (int j = 0; j < 4; ++j)
#pragma unroll
      for (int i = 0; i < 4; ++i)
        acc[i][j] = __builtin_amdgcn_mfma_f32_16x16x32_bf16(af[i], bf[j], acc[i][j], 0, 0, 0);
    __syncthreads();
    cur ^= 1;
  }
#undef STAGEB

#pragma unroll
  for (int i = 0; i < 4; ++i)
#pragma unroll
    for (int cc = 0; cc < 4; ++cc) {
      const int p = mty * 128 + wm + i * 16 + fq * 4 + cc;
      const int tok = tokmap[p];
      if (tok >= 0) {
#pragma unroll
        for (int j = 0; j < 4; ++j)
          atomicAdd(&out[(size_t)tok * HH + ncol + wn + j * 16 + fr], acc[i][j][cc]);
      }
    }
}

// ---------------- launcher ----------------
extern "C" void kernel_launch(void* const* d_in, const int* in_sizes, int n_in,
                              void* d_out, int out_size, void* d_ws, size_t ws_size,
                              hipStream_t stream) {
  (void)in_sizes; (void)n_in; (void)ws_size;
  const float* x = (const float*)d_in[0];
  const float* rw = (const float*)d_in[1];
  const float* gate_w = (const float*)d_in[2];
  const float* up_w = (const float*)d_in[3];
  const float* down_w = (const float*)d_in[4];
  const float* sh_gate = (const float*)d_in[5];
  const float* sh_up = (const float*)d_in[6];
  const float* sh_down = (const float*)d_in[7];
  float* out = (float*)d_out;

  char* ws = (char*)d_ws;
  size_t off = 0;
  u16* Xc = (u16*)(ws + off);  off += (size_t)(RSLOTS + TT) * HH * sizeof(u16);   // 7.9MB
  u16* P = (u16*)(ws + off);   off += (size_t)(RSLOTS + TT) * II * sizeof(u16);   // 21MB
  u16* Wgt = (u16*)(ws + off); off += (size_t)9 * 16 * 24 * 4096 * sizeof(u16);   // 28.3MB
  u16* Wut = (u16*)(ws + off); off += (size_t)9 * 16 * 24 * 4096 * sizeof(u16);   // 28.3MB
  u16* Wdt = (u16*)(ws + off); off += (size_t)9 * 6 * 64 * 4096 * sizeof(u16);    // 28.3MB
  float* score = (float*)(ws + off);   off += TT * sizeof(float);
  int* list = (int*)(ws + off);        off += (size_t)NE * TT * sizeof(int);
  int* cnt = (int*)(ws + off);         off += 16 * sizeof(int);
  float* probsum = (float*)(ws + off); off += 16 * sizeof(float);
  int* meta = (int*)(ws + off);        off += 64 * sizeof(int);
  int* tokmap = (int*)(ws + off);

  hipMemsetAsync(d_out, 0, (size_t)out_size * sizeof(float), stream);
  hipMemsetAsync(cnt, 0, 16 * sizeof(int) + 16 * sizeof(float), stream);
  wconv_router_kernel<<<dim3(WBLK + 512), dim3(256), 0, stream>>>(
      gate_w, up_w, down_w, sh_gate, sh_up, sh_down, Wgt, Wut, Wdt, x, rw, score,
      list, cnt, probsum);
  plan_kernel<<<dim3(1), dim3(64), 0, stream>>>(cnt, probsum, meta, out);
  gather_kernel<<<dim3(1920), dim3(256), 0, stream>>>(x, score, list, cnt, meta, Xc,
                                                      tokmap);
  stageA_kernel<<<dim3(16, 40, 1), dim3(256), 0, stream>>>(Xc, meta, Wgt, Wut, P);
  stageB_kernel<<<dim3(6, 40, 1), dim3(256), 0, stream>>>(P, meta, tokmap, Wdt, out);
}

// Round 10
// 173.066 us; speedup vs baseline: 1.0548x; 1.0548x over previous
//
#include <hip/hip_runtime.h>
#include <hip/hip_bf16.h>

// MoE MLP top-1 + shared expert. T=2048 H=768 I=2048 E=8, f32 in/out.
// R10: wconv = R5's one-shot per-chunk body (plain f32x4 loads, LDS transpose,
//      8.8KB LDS, best measured 2.4 TB/s) with router fused into the grid.
//      stageA/stageB at 3 blocks/CU. Stages/gather/plan = R9 (validated).
// Chunk = 128 n x 32 k bf16 (4096 u16 = 8KB), in-chunk addr:
//   ((n>>4)&7)*512 + ((k>>3)&3)*128 + (n&15)*8 + (k&7)
// gll16 copies chunks linearly in the GEMMs; fragment reads linear-in-lane.

#define TT 2048
#define HH 768
#define II 2048
#define NE 8
#define RSLOTS 3072   // routed padded slots (24 tiles of 128)
#define LDSW 138      // wconv LDS row stride (u16)
#define WCHUNKS 10368 // 6912 gate/up + 3456 down one-chunk blocks

typedef unsigned short u16;
typedef unsigned int u32;
typedef short s16x8 __attribute__((ext_vector_type(8)));
typedef u16 u16x8 __attribute__((ext_vector_type(8)));
typedef float f32x4 __attribute__((ext_vector_type(4)));

__device__ __forceinline__ u16 f2bf(float f) {  // f32 -> bf16 RNE
  u32 u = __builtin_bit_cast(u32, f);
  return (u16)((u + 0x7FFFu + ((u >> 16) & 1u)) >> 16);
}

typedef __attribute__((address_space(3))) u32 lds_u32;
typedef const __attribute__((address_space(1))) u32 glb_u32;
__device__ __forceinline__ void gll16(const void* g, void* l) {
  // global src per-lane; LDS dest wave-uniform base + lane*16 (linear)
  __builtin_amdgcn_global_load_lds((glb_u32*)g,
                                   (lds_u32*)(u32)(unsigned long long)l, 16, 0, 0);
}

// ---------------- fused wconv + router ----------------
// wconv chunk ids: [0,6912) gate/up (9 x {g,u} x 16 nt x 24 kc);
//                  [6912,10368) down (9 x 6 nt x 64 kc). expert 8 = shared.
// router blocks: blockIdx >= WCHUNKS (512 blocks x 4 tokens).
__global__ __launch_bounds__(256) void wconv_router_kernel(
    const float* __restrict__ gate_w, const float* __restrict__ up_w,
    const float* __restrict__ down_w, const float* __restrict__ sh_gate,
    const float* __restrict__ sh_up, const float* __restrict__ sh_down,
    u16* __restrict__ Wgt, u16* __restrict__ Wut, u16* __restrict__ Wdt,
    const float* __restrict__ x, const float* __restrict__ rw,
    float* __restrict__ score, int* __restrict__ list, int* __restrict__ cnt,
    float* __restrict__ probsum) {
  __shared__ u16 lds[32 * LDSW];  // 8.8 KB
  const int t = threadIdx.x;

  if (blockIdx.x >= WCHUNKS) {
    // ---- router: one wave per token ----
    const int tok = (int)(((blockIdx.x - WCHUNKS) * 256 + t) >> 6);
    const int lane = t & 63;
    if (tok >= TT) return;
    double acc[NE];
#pragma unroll
    for (int e = 0; e < NE; ++e) acc[e] = 0.0;
    const float* xr = x + (size_t)tok * HH;
    for (int h = lane; h < HH; h += 64) {
      const double xv = (double)xr[h];
#pragma unroll
      for (int e = 0; e < NE; ++e) acc[e] += xv * (double)rw[h * NE + e];
    }
#pragma unroll
    for (int off = 32; off > 0; off >>= 1) {
#pragma unroll
      for (int e = 0; e < NE; ++e) acc[e] += __shfl_xor(acc[e], off);
    }
    if (lane == 0) {
      int best = 0;
#pragma unroll
      for (int e = 1; e < NE; ++e)
        if (acc[e] > acc[best]) best = e;  // strict > == first-max (jnp.argmax)
      const float sc = 1.0f / (1.0f + __expf((float)(-acc[best])));
      score[tok] = sc;
      const int pos = atomicAdd(&cnt[best], 1);
      list[best * TT + pos] = tok;
      atomicAdd(&probsum[best], sc);
    }
    return;
  }

  // ---- wconv: one [32k x 128n] chunk per block (R5 body, validated) ----
  const int id = blockIdx.x;
  const float* src;
  u16* dst;
  int N, n0, k0;
  if (id < 6912) {
    const int m = id / 384;  // 0..17: expert e=m>>1, mat=m&1
    const int r = id % 384;
    const int e = m >> 1;
    const int nt = r / 24, kc = r % 24;
    src = (m & 1) ? (e < 8 ? up_w + (size_t)e * HH * II : sh_up)
                  : (e < 8 ? gate_w + (size_t)e * HH * II : sh_gate);
    N = II; n0 = nt * 128; k0 = kc * 32;
    dst = ((m & 1) ? Wut : Wgt) + ((size_t)(e * 16 + nt) * 24 + kc) * 4096;
  } else {
    const int id2 = id - 6912;
    const int e = id2 / 384;
    const int r = id2 % 384;
    const int nt = r / 64, kc = r % 64;
    src = (e < 8) ? down_w + (size_t)e * II * HH : sh_down;
    N = HH; n0 = nt * 128; k0 = kc * 32;
    dst = Wdt + ((size_t)(e * 6 + nt) * 64 + kc) * 4096;
  }
  // phase 1: coalesced f32x4 reads along n; bf16 rows into LDS
  {
    const int k = t >> 3;         // 0..31
    const int nb = (t & 7) * 16;  // 16 consecutive n per thread
    const float* rp = src + (size_t)(k0 + k) * N + n0 + nb;
    const f32x4 a0 = *reinterpret_cast<const f32x4*>(rp);
    const f32x4 a1 = *reinterpret_cast<const f32x4*>(rp + 4);
    const f32x4 a2 = *reinterpret_cast<const f32x4*>(rp + 8);
    const f32x4 a3 = *reinterpret_cast<const f32x4*>(rp + 12);
    u16x8 w0, w1;
#pragma unroll
    for (int j = 0; j < 4; ++j) {
      w0[j] = f2bf(a0[j]); w0[j + 4] = f2bf(a1[j]);
      w1[j] = f2bf(a2[j]); w1[j + 4] = f2bf(a3[j]);
    }
    *reinterpret_cast<u16x8*>(&lds[k * LDSW + nb]) = w0;
    *reinterpret_cast<u16x8*>(&lds[k * LDSW + nb + 8]) = w1;
  }
  __syncthreads();
  // phase 2: k-minor gather from LDS, coalesced u16x8 stores
#pragma unroll
  for (int r = 0; r < 2; ++r) {
    const int o = t + r * 256;  // 0..511
    const int fr = o & 15, fq = (o >> 4) & 3, nq = o >> 6;
    u16x8 w;
#pragma unroll
    for (int j = 0; j < 8; ++j) w[j] = lds[(fq * 8 + j) * LDSW + nq * 16 + fr];
    *reinterpret_cast<u16x8*>(&dst[o * 8]) = w;
  }
}

// ---------------- plan: padded segments + tile->expert + loss ----------------
__global__ void plan_kernel(const int* __restrict__ cnt, const float* __restrict__ probsum,
                            int* __restrict__ meta, float* __restrict__ out) {
  if (threadIdx.x == 0) {
    int S = 0;
    for (int e = 0; e < NE; ++e) {
      meta[e] = S;
      const int pad = (cnt[e] + 127) & ~127;
      for (int t = S >> 7; t < (S + pad) >> 7; ++t) meta[16 + t] = e;
      S += pad;
    }
    meta[8] = S;
    for (int t = S >> 7; t < 24; ++t) meta[16 + t] = 0;
    float s = 0.0f;
    for (int e = 0; e < NE; ++e) s += (float)cnt[e] * probsum[e];
    out[(size_t)TT * HH] = s * (0.001f * (float)NE / ((float)TT * (float)TT));
  }
}

// ---------------- gather: x -> tiled bf16 Xc (+tokmap) ----------------
__global__ __launch_bounds__(256) void gather_kernel(
    const float* __restrict__ x, const float* __restrict__ score,
    const int* __restrict__ list, const int* __restrict__ cnt,
    const int* __restrict__ meta, u16* __restrict__ Xc, int* __restrict__ tokmap) {
  const int task = blockIdx.x * 4 + (threadIdx.x >> 6);
  const int lane = threadIdx.x & 63;
  const int pb = task / 24;  // 16-row block, 0..319
  const int c = task % 24;   // k chunk
  const int fq = lane >> 4, fr = lane & 15;
  const int p = pb * 16 + fr;
  int tok;
  float sc;
  if (p >= RSLOTS) {
    tok = p - RSLOTS;
    sc = 1.0f;
  } else {
    const int e = meta[16 + (p >> 7)];
    const int idx = p - meta[e];
    tok = (idx >= 0 && idx < cnt[e]) ? list[e * TT + idx] : -1;
    sc = (tok >= 0) ? score[tok] : 0.0f;
  }
  u16x8 w = {0, 0, 0, 0, 0, 0, 0, 0};
  if (tok >= 0) {
    const float* xp = x + (size_t)tok * HH + c * 32 + fq * 8;
    const f32x4 a = *reinterpret_cast<const f32x4*>(xp);
    const f32x4 b = *reinterpret_cast<const f32x4*>(xp + 4);
#pragma unroll
    for (int j = 0; j < 4; ++j) {
      w[j] = f2bf(a[j] * sc);
      w[j + 4] = f2bf(b[j] * sc);
    }
  }
  *reinterpret_cast<u16x8*>(&Xc[((size_t)(pb >> 3) * 24 + c) * 4096 + (pb & 7) * 512 +
                                lane * 8]) = w;
  if (c == 0 && fq == 0) tokmap[p] = tok;
}

// ---------------- stage A: P = silu(Xc Wg) * (Xc Wu) ----------------
// grid (16 nt, 40 mty): mty<24 routed (early-exit past Rp), >=24 shared (e=8).
__global__ __launch_bounds__(256, 3) void stageA_kernel(
    const u16* __restrict__ Xc, const int* __restrict__ meta,
    const u16* __restrict__ Wgt, const u16* __restrict__ Wut, u16* __restrict__ P) {
  const int mty = blockIdx.y, nt = blockIdx.x;
  int e;
  if (mty < 24) {
    if (mty * 128 >= meta[8]) return;
    e = meta[16 + mty];
  } else {
    e = 8;
  }
  const u16* wg = Wgt + (size_t)(e * 16 + nt) * 24 * 4096;
  const u16* wu = Wut + (size_t)(e * 16 + nt) * 24 * 4096;
  const u16* xa = Xc + (size_t)mty * 24 * 4096;

  __shared__ u16 As[2][4096], Bgs[2][4096], Bus[2][4096];

  const int tid = threadIdx.x, lane = tid & 63, wid = tid >> 6;
  const int fr = lane & 15, fq = lane >> 4;
  const int wm4 = (wid >> 1) * 4;  // row 16-block base
  const int wn4 = (wid & 1) * 4;   // col 16-block base
  const int wn = (wid & 1) * 64;
  const int ncol = nt * 128;
  const int so = wid * 1024 + lane * 8;  // gll global src offset (u16)
  const int sl = wid * 1024;             // gll LDS dst offset (u16), wave-uniform

  f32x4 accg[4][4], accu[4][4];
#pragma unroll
  for (int i = 0; i < 4; ++i)
#pragma unroll
    for (int j = 0; j < 4; ++j) {
      accg[i][j] = f32x4{0.f, 0.f, 0.f, 0.f};
      accu[i][j] = f32x4{0.f, 0.f, 0.f, 0.f};
    }

  // full chunk = 4096 u16; 4 waves x 2 gll16 x 512 u16 each
#define STAGE(c, buf)                                               \
  {                                                                 \
    gll16(xa + (size_t)(c) * 4096 + so, &As[buf][sl]);              \
    gll16(xa + (size_t)(c) * 4096 + so + 512, &As[buf][sl + 512]);  \
    gll16(wg + (size_t)(c) * 4096 + so, &Bgs[buf][sl]);             \
    gll16(wg + (size_t)(c) * 4096 + so + 512, &Bgs[buf][sl + 512]); \
    gll16(wu + (size_t)(c) * 4096 + so, &Bus[buf][sl]);             \
    gll16(wu + (size_t)(c) * 4096 + so + 512, &Bus[buf][sl + 512]); \
  }

  STAGE(0, 0)
  __syncthreads();
  int cur = 0;
  for (int c = 0; c < 24; ++c) {
    if (c < 23) STAGE(c + 1, cur ^ 1)
    s16x8 af[4], bg[4], bu[4];
#pragma unroll
    for (int i = 0; i < 4; ++i) {
      af[i] = *reinterpret_cast<const s16x8*>(&As[cur][(wm4 + i) * 512 + fq * 128 + fr * 8]);
      bg[i] = *reinterpret_cast<const s16x8*>(&Bgs[cur][(wn4 + i) * 512 + fq * 128 + fr * 8]);
      bu[i] = *reinterpret_cast<const s16x8*>(&Bus[cur][(wn4 + i) * 512 + fq * 128 + fr * 8]);
    }
#pragma unroll
    for (int j = 0; j < 4; ++j)
#pragma unroll
      for (int i = 0; i < 4; ++i) {
        accg[i][j] = __builtin_amdgcn_mfma_f32_16x16x32_bf16(af[i], bg[j], accg[i][j], 0, 0, 0);
        accu[i][j] = __builtin_amdgcn_mfma_f32_16x16x32_bf16(af[i], bu[j], accu[i][j], 0, 0, 0);
      }
    __syncthreads();
    cur ^= 1;
  }
#undef STAGE

  // epilogue: silu(g)*u -> P tiled bf16 (C/D: row=fq*4+reg, col=fr)
#pragma unroll
  for (int i = 0; i < 4; ++i)
#pragma unroll
    for (int cc = 0; cc < 4; ++cc) {
      const int rlo = fq * 4 + cc;  // row & 15 within 16-block (wm4+i)
#pragma unroll
      for (int j = 0; j < 4; ++j) {
        const int k = ncol + wn + j * 16 + fr;  // global i-col
        const float gv = accg[i][j][cc];
        const float val = (gv / (1.0f + __expf(-gv))) * accu[i][j][cc];
        P[((size_t)mty * 64 + (k >> 5)) * 4096 + (size_t)(wm4 + i) * 512 +
          ((k >> 3) & 3) * 128 + rlo * 8 + (k & 7)] = f2bf(val);
      }
    }
}

// ---------------- stage B: out += P Wd (atomicAdd, out pre-zeroed) ----------------
// grid (6 nt, 40 mty); each out element gets one shared + at most one routed add.
__global__ __launch_bounds__(256, 3) void stageB_kernel(
    const u16* __restrict__ P, const int* __restrict__ meta,
    const int* __restrict__ tokmap, const u16* __restrict__ Wdt,
    float* __restrict__ out) {
  const int mty = blockIdx.y, nt = blockIdx.x;
  int e;
  if (mty < 24) {
    if (mty * 128 >= meta[8]) return;
    e = meta[16 + mty];
  } else {
    e = 8;
  }
  const u16* wd = Wdt + (size_t)(e * 6 + nt) * 64 * 4096;
  const u16* pa = P + (size_t)mty * 64 * 4096;

  __shared__ u16 As[2][4096], Bs[2][4096];

  const int tid = threadIdx.x, lane = tid & 63, wid = tid >> 6;
  const int fr = lane & 15, fq = lane >> 4;
  const int wm4 = (wid >> 1) * 4;
  const int wn4 = (wid & 1) * 4;
  const int wm = (wid >> 1) * 64;
  const int wn = (wid & 1) * 64;
  const int ncol = nt * 128;
  const int so = wid * 1024 + lane * 8;
  const int sl = wid * 1024;

  f32x4 acc[4][4];
#pragma unroll
  for (int i = 0; i < 4; ++i)
#pragma unroll
    for (int j = 0; j < 4; ++j) acc[i][j] = f32x4{0.f, 0.f, 0.f, 0.f};

#define STAGEB(c, buf)                                              \
  {                                                                 \
    gll16(pa + (size_t)(c) * 4096 + so, &As[buf][sl]);              \
    gll16(pa + (size_t)(c) * 4096 + so + 512, &As[buf][sl + 512]);  \
    gll16(wd + (size_t)(c) * 4096 + so, &Bs[buf][sl]);              \
    gll16(wd + (size_t)(c) * 4096 + so + 512, &Bs[buf][sl + 512]);  \
  }

  STAGEB(0, 0)
  __syncthreads();
  int cur = 0;
  for (int c = 0; c < 64; ++c) {
    if (c < 63) STAGEB(c + 1, cur ^ 1)
    s16x8 af[4], bf[4];
#pragma unroll
    for (int i = 0; i < 4; ++i) {
      af[i] = *reinterpret_cast<const s16x8*>(&As[cur][(wm4 + i) * 512 + fq * 128 + fr * 8]);
      bf[i] = *reinterpret_cast<const s16x8*>(&Bs[cur][(wn4 + i) * 512 + fq * 128 + fr * 8]);
    }
#pragma unroll
    for (int j = 0; j < 4; ++j)
#pragma unroll
      for (int i = 0; i < 4; ++i)
        acc[i][j] = __builtin_amdgcn_mfma_f32_16x16x32_bf16(af[i], bf[j], acc[i][j], 0, 0, 0);
    __syncthreads();
    cur ^= 1;
  }
#undef STAGEB

#pragma unroll
  for (int i = 0; i < 4; ++i)
#pragma unroll
    for (int cc = 0; cc < 4; ++cc) {
      const int p = mty * 128 + wm + i * 16 + fq * 4 + cc;
      const int tok = tokmap[p];
      if (tok >= 0) {
#pragma unroll
        for (int j = 0; j < 4; ++j)
          atomicAdd(&out[(size_t)tok * HH + ncol + wn + j * 16 + fr], acc[i][j][cc]);
      }
    }
}

// ---------------- launcher ----------------
extern "C" void kernel_launch(void* const* d_in, const int* in_sizes, int n_in,
                              void* d_out, int out_size, void* d_ws, size_t ws_size,
                              hipStream_t stream) {
  (void)in_sizes; (void)n_in; (void)ws_size;
  const float* x = (const float*)d_in[0];
  const float* rw = (const float*)d_in[1];
  const float* gate_w = (const float*)d_in[2];
  const float* up_w = (const float*)d_in[3];
  const float* down_w = (const float*)d_in[4];
  const float* sh_gate = (const float*)d_in[5];
  const float* sh_up = (const float*)d_in[6];
  const float* sh_down = (const float*)d_in[7];
  float* out = (float*)d_out;

  char* ws = (char*)d_ws;
  size_t off = 0;
  u16* Xc = (u16*)(ws + off);  off += (size_t)(RSLOTS + TT) * HH * sizeof(u16);   // 7.9MB
  u16* P = (u16*)(ws + off);   off += (size_t)(RSLOTS + TT) * II * sizeof(u16);   // 21MB
  u16* Wgt = (u16*)(ws + off); off += (size_t)9 * 16 * 24 * 4096 * sizeof(u16);   // 28.3MB
  u16* Wut = (u16*)(ws + off); off += (size_t)9 * 16 * 24 * 4096 * sizeof(u16);   // 28.3MB
  u16* Wdt = (u16*)(ws + off); off += (size_t)9 * 6 * 64 * 4096 * sizeof(u16);    // 28.3MB
  float* score = (float*)(ws + off);   off += TT * sizeof(float);
  int* list = (int*)(ws + off);        off += (size_t)NE * TT * sizeof(int);
  int* cnt = (int*)(ws + off);         off += 16 * sizeof(int);
  float* probsum = (float*)(ws + off); off += 16 * sizeof(float);
  int* meta = (int*)(ws + off);        off += 64 * sizeof(int);
  int* tokmap = (int*)(ws + off);

  hipMemsetAsync(d_out, 0, (size_t)out_size * sizeof(float), stream);
  hipMemsetAsync(cnt, 0, 16 * sizeof(int) + 16 * sizeof(float), stream);
  wconv_router_kernel<<<dim3(WCHUNKS + 512), dim3(256), 0, stream>>>(
      gate_w, up_w, down_w, sh_gate, sh_up, sh_down, Wgt, Wut, Wdt, x, rw, score,
      list, cnt, probsum);
  plan_kernel<<<dim3(1), dim3(64), 0, stream>>>(cnt, probsum, meta, out);
  gather_kernel<<<dim3(1920), dim3(256), 0, stream>>>(x, score, list, cnt, meta, Xc,
                                                      tokmap);
  stageA_kernel<<<dim3(16, 40, 1), dim3(256), 0, stream>>>(Xc, meta, Wgt, Wut, P);
  stageB_kernel<<<dim3(6, 40, 1), dim3(256), 0, stream>>>(P, meta, tokmap, Wdt, out);
}

// Round 11
// 172.980 us; speedup vs baseline: 1.0553x; 1.0005x over previous
//
#include <hip/hip_runtime.h>
#include <hip/hip_bf16.h>

// MoE MLP top-1 + shared expert. T=2048 H=768 I=2048 E=8, f32 in/out.
// R11: wconv = R5 one-shot body, but block order kc-major/nt-minor and dst
//      layout (e,kc,nt) -> concurrent blocks read AND write contiguous spans
//      (DRAM row locality). Router blocks lead the fused grid. Stage kernels
//      use R8's validated (e,kc,nt) strides. Everything else = R10.
// Chunk = 128 n x 32 k bf16 (4096 u16 = 8KB), in-chunk addr:
//   ((n>>4)&7)*512 + ((k>>3)&3)*128 + (n&15)*8 + (k&7)
// gll16 copies chunks linearly in the GEMMs; fragment reads linear-in-lane.

#define TT 2048
#define HH 768
#define II 2048
#define NE 8
#define RSLOTS 3072   // routed padded slots (24 tiles of 128)
#define LDSW 138      // wconv LDS row stride (u16)
#define RBLK 512      // router blocks (lead the fused grid)
#define WCHUNKS 10368 // 6912 gate/up + 3456 down one-chunk blocks

typedef unsigned short u16;
typedef unsigned int u32;
typedef short s16x8 __attribute__((ext_vector_type(8)));
typedef u16 u16x8 __attribute__((ext_vector_type(8)));
typedef float f32x4 __attribute__((ext_vector_type(4)));

__device__ __forceinline__ u16 f2bf(float f) {  // f32 -> bf16 RNE
  u32 u = __builtin_bit_cast(u32, f);
  return (u16)((u + 0x7FFFu + ((u >> 16) & 1u)) >> 16);
}

typedef __attribute__((address_space(3))) u32 lds_u32;
typedef const __attribute__((address_space(1))) u32 glb_u32;
__device__ __forceinline__ void gll16(const void* g, void* l) {
  // global src per-lane; LDS dest wave-uniform base + lane*16 (linear)
  __builtin_amdgcn_global_load_lds((glb_u32*)g,
                                   (lds_u32*)(u32)(unsigned long long)l, 16, 0, 0);
}

// ---------------- fused router + wconv ----------------
// blocks [0,RBLK): router (4 waves x 1 token each).
// blocks [RBLK, RBLK+WCHUNKS): wconv, id = blockIdx.x - RBLK:
//   id<6912: gate/up. m=id/384 (e=m>>1, mat=m&1), r=id%384, kc=r>>4, nt=r&15.
//   id>=6912: down. e=(id-6912)/384, r=%384, kc=r/6, nt=r%6.
// dst layout (e,kc,nt): Wg/Wu chunk = ((e*24+kc)*16+nt); Wd = ((e*64+kc)*6+nt).
// Consecutive blocks share kc -> contiguous read AND write spans.
__global__ __launch_bounds__(256) void wconv_router_kernel(
    const float* __restrict__ gate_w, const float* __restrict__ up_w,
    const float* __restrict__ down_w, const float* __restrict__ sh_gate,
    const float* __restrict__ sh_up, const float* __restrict__ sh_down,
    u16* __restrict__ Wgt, u16* __restrict__ Wut, u16* __restrict__ Wdt,
    const float* __restrict__ x, const float* __restrict__ rw,
    float* __restrict__ score, int* __restrict__ list, int* __restrict__ cnt,
    float* __restrict__ probsum) {
  __shared__ u16 lds[32 * LDSW];  // 8.8 KB
  const int t = threadIdx.x;

  if (blockIdx.x < RBLK) {
    // ---- router: one wave per token ----
    const int tok = (int)((blockIdx.x * 256 + t) >> 6);
    const int lane = t & 63;
    if (tok >= TT) return;
    double acc[NE];
#pragma unroll
    for (int e = 0; e < NE; ++e) acc[e] = 0.0;
    const float* xr = x + (size_t)tok * HH;
    for (int h = lane; h < HH; h += 64) {
      const double xv = (double)xr[h];
#pragma unroll
      for (int e = 0; e < NE; ++e) acc[e] += xv * (double)rw[h * NE + e];
    }
#pragma unroll
    for (int off = 32; off > 0; off >>= 1) {
#pragma unroll
      for (int e = 0; e < NE; ++e) acc[e] += __shfl_xor(acc[e], off);
    }
    if (lane == 0) {
      int best = 0;
#pragma unroll
      for (int e = 1; e < NE; ++e)
        if (acc[e] > acc[best]) best = e;  // strict > == first-max (jnp.argmax)
      const float sc = 1.0f / (1.0f + __expf((float)(-acc[best])));
      score[tok] = sc;
      const int pos = atomicAdd(&cnt[best], 1);
      list[best * TT + pos] = tok;
      atomicAdd(&probsum[best], sc);
    }
    return;
  }

  // ---- wconv: one [32k x 128n] chunk per block (R5 body) ----
  const int id = blockIdx.x - RBLK;
  const float* src;
  u16* dst;
  int N, n0, k0;
  if (id < 6912) {
    const int m = id / 384;  // 0..17: expert e=m>>1, mat=m&1
    const int r = id % 384;
    const int e = m >> 1;
    const int kc = r >> 4, nt = r & 15;  // kc-major, nt-minor
    src = (m & 1) ? (e < 8 ? up_w + (size_t)e * HH * II : sh_up)
                  : (e < 8 ? gate_w + (size_t)e * HH * II : sh_gate);
    N = II; n0 = nt * 128; k0 = kc * 32;
    dst = ((m & 1) ? Wut : Wgt) + ((size_t)(e * 24 + kc) * 16 + nt) * 4096;
  } else {
    const int id2 = id - 6912;
    const int e = id2 / 384;
    const int r = id2 % 384;
    const int kc = r / 6, nt = r % 6;  // kc-major, nt-minor
    src = (e < 8) ? down_w + (size_t)e * II * HH : sh_down;
    N = HH; n0 = nt * 128; k0 = kc * 32;
    dst = Wdt + ((size_t)(e * 64 + kc) * 6 + nt) * 4096;
  }
  // phase 1: coalesced f32x4 reads along n; bf16 rows into LDS
  {
    const int k = t >> 3;         // 0..31
    const int nb = (t & 7) * 16;  // 16 consecutive n per thread
    const float* rp = src + (size_t)(k0 + k) * N + n0 + nb;
    const f32x4 a0 = *reinterpret_cast<const f32x4*>(rp);
    const f32x4 a1 = *reinterpret_cast<const f32x4*>(rp + 4);
    const f32x4 a2 = *reinterpret_cast<const f32x4*>(rp + 8);
    const f32x4 a3 = *reinterpret_cast<const f32x4*>(rp + 12);
    u16x8 w0, w1;
#pragma unroll
    for (int j = 0; j < 4; ++j) {
      w0[j] = f2bf(a0[j]); w0[j + 4] = f2bf(a1[j]);
      w1[j] = f2bf(a2[j]); w1[j + 4] = f2bf(a3[j]);
    }
    *reinterpret_cast<u16x8*>(&lds[k * LDSW + nb]) = w0;
    *reinterpret_cast<u16x8*>(&lds[k * LDSW + nb + 8]) = w1;
  }
  __syncthreads();
  // phase 2: k-minor gather from LDS, coalesced u16x8 stores
#pragma unroll
  for (int r = 0; r < 2; ++r) {
    const int o = t + r * 256;  // 0..511
    const int fr = o & 15, fq = (o >> 4) & 3, nq = o >> 6;
    u16x8 w;
#pragma unroll
    for (int j = 0; j < 8; ++j) w[j] = lds[(fq * 8 + j) * LDSW + nq * 16 + fr];
    *reinterpret_cast<u16x8*>(&dst[o * 8]) = w;
  }
}

// ---------------- plan: padded segments + tile->expert + loss ----------------
__global__ void plan_kernel(const int* __restrict__ cnt, const float* __restrict__ probsum,
                            int* __restrict__ meta, float* __restrict__ out) {
  if (threadIdx.x == 0) {
    int S = 0;
    for (int e = 0; e < NE; ++e) {
      meta[e] = S;
      const int pad = (cnt[e] + 127) & ~127;
      for (int t = S >> 7; t < (S + pad) >> 7; ++t) meta[16 + t] = e;
      S += pad;
    }
    meta[8] = S;
    for (int t = S >> 7; t < 24; ++t) meta[16 + t] = 0;
    float s = 0.0f;
    for (int e = 0; e < NE; ++e) s += (float)cnt[e] * probsum[e];
    out[(size_t)TT * HH] = s * (0.001f * (float)NE / ((float)TT * (float)TT));
  }
}

// ---------------- gather: x -> tiled bf16 Xc (+tokmap) ----------------
__global__ __launch_bounds__(256) void gather_kernel(
    const float* __restrict__ x, const float* __restrict__ score,
    const int* __restrict__ list, const int* __restrict__ cnt,
    const int* __restrict__ meta, u16* __restrict__ Xc, int* __restrict__ tokmap) {
  const int task = blockIdx.x * 4 + (threadIdx.x >> 6);
  const int lane = threadIdx.x & 63;
  const int pb = task / 24;  // 16-row block, 0..319
  const int c = task % 24;   // k chunk
  const int fq = lane >> 4, fr = lane & 15;
  const int p = pb * 16 + fr;
  int tok;
  float sc;
  if (p >= RSLOTS) {
    tok = p - RSLOTS;
    sc = 1.0f;
  } else {
    const int e = meta[16 + (p >> 7)];
    const int idx = p - meta[e];
    tok = (idx >= 0 && idx < cnt[e]) ? list[e * TT + idx] : -1;
    sc = (tok >= 0) ? score[tok] : 0.0f;
  }
  u16x8 w = {0, 0, 0, 0, 0, 0, 0, 0};
  if (tok >= 0) {
    const float* xp = x + (size_t)tok * HH + c * 32 + fq * 8;
    const f32x4 a = *reinterpret_cast<const f32x4*>(xp);
    const f32x4 b = *reinterpret_cast<const f32x4*>(xp + 4);
#pragma unroll
    for (int j = 0; j < 4; ++j) {
      w[j] = f2bf(a[j] * sc);
      w[j + 4] = f2bf(b[j] * sc);
    }
  }
  *reinterpret_cast<u16x8*>(&Xc[((size_t)(pb >> 3) * 24 + c) * 4096 + (pb & 7) * 512 +
                                lane * 8]) = w;
  if (c == 0 && fq == 0) tokmap[p] = tok;
}

// ---------------- stage A: P = silu(Xc Wg) * (Xc Wu) ----------------
// grid (16 nt, 40 mty): mty<24 routed (early-exit past Rp), >=24 shared (e=8).
__global__ __launch_bounds__(256, 3) void stageA_kernel(
    const u16* __restrict__ Xc, const int* __restrict__ meta,
    const u16* __restrict__ Wgt, const u16* __restrict__ Wut, u16* __restrict__ P) {
  const int mty = blockIdx.y, nt = blockIdx.x;
  int e;
  if (mty < 24) {
    if (mty * 128 >= meta[8]) return;
    e = meta[16 + mty];
  } else {
    e = 8;
  }
  // chunk (e, c, nt): stride between c = 16*4096 u16
  const u16* wg = Wgt + ((size_t)e * 24 * 16 + nt) * 4096;
  const u16* wu = Wut + ((size_t)e * 24 * 16 + nt) * 4096;
  const u16* xa = Xc + (size_t)mty * 24 * 4096;

  __shared__ u16 As[2][4096], Bgs[2][4096], Bus[2][4096];

  const int tid = threadIdx.x, lane = tid & 63, wid = tid >> 6;
  const int fr = lane & 15, fq = lane >> 4;
  const int wm4 = (wid >> 1) * 4;  // row 16-block base
  const int wn4 = (wid & 1) * 4;   // col 16-block base
  const int wn = (wid & 1) * 64;
  const int ncol = nt * 128;
  const int so = wid * 1024 + lane * 8;  // gll global src offset (u16)
  const int sl = wid * 1024;             // gll LDS dst offset (u16), wave-uniform

  f32x4 accg[4][4], accu[4][4];
#pragma unroll
  for (int i = 0; i < 4; ++i)
#pragma unroll
    for (int j = 0; j < 4; ++j) {
      accg[i][j] = f32x4{0.f, 0.f, 0.f, 0.f};
      accu[i][j] = f32x4{0.f, 0.f, 0.f, 0.f};
    }

  // full chunk = 4096 u16; 4 waves x 2 gll16 x 512 u16 each
#define STAGE(c, buf)                                                 \
  {                                                                   \
    gll16(xa + (size_t)(c) * 4096 + so, &As[buf][sl]);                \
    gll16(xa + (size_t)(c) * 4096 + so + 512, &As[buf][sl + 512]);    \
    gll16(wg + (size_t)(c) * 65536 + so, &Bgs[buf][sl]);              \
    gll16(wg + (size_t)(c) * 65536 + so + 512, &Bgs[buf][sl + 512]);  \
    gll16(wu + (size_t)(c) * 65536 + so, &Bus[buf][sl]);              \
    gll16(wu + (size_t)(c) * 65536 + so + 512, &Bus[buf][sl + 512]);  \
  }

  STAGE(0, 0)
  __syncthreads();
  int cur = 0;
  for (int c = 0; c < 24; ++c) {
    if (c < 23) STAGE(c + 1, cur ^ 1)
    s16x8 af[4], bg[4], bu[4];
#pragma unroll
    for (int i = 0; i < 4; ++i) {
      af[i] = *reinterpret_cast<const s16x8*>(&As[cur][(wm4 + i) * 512 + fq * 128 + fr * 8]);
      bg[i] = *reinterpret_cast<const s16x8*>(&Bgs[cur][(wn4 + i) * 512 + fq * 128 + fr * 8]);
      bu[i] = *reinterpret_cast<const s16x8*>(&Bus[cur][(wn4 + i) * 512 + fq * 128 + fr * 8]);
    }
#pragma unroll
    for (int j = 0; j < 4; ++j)
#pragma unroll
      for (int i = 0; i < 4; ++i) {
        accg[i][j] = __builtin_amdgcn_mfma_f32_16x16x32_bf16(af[i], bg[j], accg[i][j], 0, 0, 0);
        accu[i][j] = __builtin_amdgcn_mfma_f32_16x16x32_bf16(af[i], bu[j], accu[i][j], 0, 0, 0);
      }
    __syncthreads();
    cur ^= 1;
  }
#undef STAGE

  // epilogue: silu(g)*u -> P tiled bf16 (C/D: row=fq*4+reg, col=fr)
#pragma unroll
  for (int i = 0; i < 4; ++i)
#pragma unroll
    for (int cc = 0; cc < 4; ++cc) {
      const int rlo = fq * 4 + cc;  // row & 15 within 16-block (wm4+i)
#pragma unroll
      for (int j = 0; j < 4; ++j) {
        const int k = ncol + wn + j * 16 + fr;  // global i-col
        const float gv = accg[i][j][cc];
        const float val = (gv / (1.0f + __expf(-gv))) * accu[i][j][cc];
        P[((size_t)mty * 64 + (k >> 5)) * 4096 + (size_t)(wm4 + i) * 512 +
          ((k >> 3) & 3) * 128 + rlo * 8 + (k & 7)] = f2bf(val);
      }
    }
}

// ---------------- stage B: out += P Wd (atomicAdd, out pre-zeroed) ----------------
// grid (6 nt, 40 mty); each out element gets one shared + at most one routed add.
__global__ __launch_bounds__(256, 3) void stageB_kernel(
    const u16* __restrict__ P, const int* __restrict__ meta,
    const int* __restrict__ tokmap, const u16* __restrict__ Wdt,
    float* __restrict__ out) {
  const int mty = blockIdx.y, nt = blockIdx.x;
  int e;
  if (mty < 24) {
    if (mty * 128 >= meta[8]) return;
    e = meta[16 + mty];
  } else {
    e = 8;
  }
  // chunk (e, c, nt): stride between c = 6*4096 u16
  const u16* wd = Wdt + ((size_t)e * 64 * 6 + nt) * 4096;
  const u16* pa = P + (size_t)mty * 64 * 4096;

  __shared__ u16 As[2][4096], Bs[2][4096];

  const int tid = threadIdx.x, lane = tid & 63, wid = tid >> 6;
  const int fr = lane & 15, fq = lane >> 4;
  const int wm4 = (wid >> 1) * 4;
  const int wn4 = (wid & 1) * 4;
  const int wm = (wid >> 1) * 64;
  const int wn = (wid & 1) * 64;
  const int ncol = nt * 128;
  const int so = wid * 1024 + lane * 8;
  const int sl = wid * 1024;

  f32x4 acc[4][4];
#pragma unroll
  for (int i = 0; i < 4; ++i)
#pragma unroll
    for (int j = 0; j < 4; ++j) acc[i][j] = f32x4{0.f, 0.f, 0.f, 0.f};

#define STAGEB(c, buf)                                                \
  {                                                                   \
    gll16(pa + (size_t)(c) * 4096 + so, &As[buf][sl]);                \
    gll16(pa + (size_t)(c) * 4096 + so + 512, &As[buf][sl + 512]);    \
    gll16(wd + (size_t)(c) * 24576 + so, &Bs[buf][sl]);               \
    gll16(wd + (size_t)(c) * 24576 + so + 512, &Bs[buf][sl + 512]);   \
  }

  STAGEB(0, 0)
  __syncthreads();
  int cur = 0;
  for (int c = 0; c < 64; ++c) {
    if (c < 63) STAGEB(c + 1, cur ^ 1)
    s16x8 af[4], bf[4];
#pragma unroll
    for (int i = 0; i < 4; ++i) {
      af[i] = *reinterpret_cast<const s16x8*>(&As[cur][(wm4 + i) * 512 + fq * 128 + fr * 8]);
      bf[i] = *reinterpret_cast<const s16x8*>(&Bs[cur][(wn4 + i) * 512 + fq * 128 + fr * 8]);
    }
#pragma unroll
    for (int j = 0; j < 4; ++j)
#pragma unroll
      for (int i = 0; i < 4; ++i)
        acc[i][j] = __builtin_amdgcn_mfma_f32_16x16x32_bf16(af[i], bf[j], acc[i][j], 0, 0, 0);
    __syncthreads();
    cur ^= 1;
  }
#undef STAGEB

#pragma unroll
  for (int i = 0; i < 4; ++i)
#pragma unroll
    for (int cc = 0; cc < 4; ++cc) {
      const int p = mty * 128 + wm + i * 16 + fq * 4 + cc;
      const int tok = tokmap[p];
      if (tok >= 0) {
#pragma unroll
        for (int j = 0; j < 4; ++j)
          atomicAdd(&out[(size_t)tok * HH + ncol + wn + j * 16 + fr], acc[i][j][cc]);
      }
    }
}

// ---------------- launcher ----------------
extern "C" void kernel_launch(void* const* d_in, const int* in_sizes, int n_in,
                              void* d_out, int out_size, void* d_ws, size_t ws_size,
                              hipStream_t stream) {
  (void)in_sizes; (void)n_in; (void)ws_size;
  const float* x = (const float*)d_in[0];
  const float* rw = (const float*)d_in[1];
  const float* gate_w = (const float*)d_in[2];
  const float* up_w = (const float*)d_in[3];
  const float* down_w = (const float*)d_in[4];
  const float* sh_gate = (const float*)d_in[5];
  const float* sh_up = (const float*)d_in[6];
  const float* sh_down = (const float*)d_in[7];
  float* out = (float*)d_out;

  char* ws = (char*)d_ws;
  size_t off = 0;
  u16* Xc = (u16*)(ws + off);  off += (size_t)(RSLOTS + TT) * HH * sizeof(u16);   // 7.9MB
  u16* P = (u16*)(ws + off);   off += (size_t)(RSLOTS + TT) * II * sizeof(u16);   // 21MB
  u16* Wgt = (u16*)(ws + off); off += (size_t)9 * 16 * 24 * 4096 * sizeof(u16);   // 28.3MB
  u16* Wut = (u16*)(ws + off); off += (size_t)9 * 16 * 24 * 4096 * sizeof(u16);   // 28.3MB
  u16* Wdt = (u16*)(ws + off); off += (size_t)9 * 6 * 64 * 4096 * sizeof(u16);    // 28.3MB
  float* score = (float*)(ws + off);   off += TT * sizeof(float);
  int* list = (int*)(ws + off);        off += (size_t)NE * TT * sizeof(int);
  int* cnt = (int*)(ws + off);         off += 16 * sizeof(int);
  float* probsum = (float*)(ws + off); off += 16 * sizeof(float);
  int* meta = (int*)(ws + off);        off += 64 * sizeof(int);
  int* tokmap = (int*)(ws + off);

  hipMemsetAsync(d_out, 0, (size_t)out_size * sizeof(float), stream);
  hipMemsetAsync(cnt, 0, 16 * sizeof(int) + 16 * sizeof(float), stream);
  wconv_router_kernel<<<dim3(RBLK + WCHUNKS), dim3(256), 0, stream>>>(
      gate_w, up_w, down_w, sh_gate, sh_up, sh_down, Wgt, Wut, Wdt, x, rw, score,
      list, cnt, probsum);
  plan_kernel<<<dim3(1), dim3(64), 0, stream>>>(cnt, probsum, meta, out);
  gather_kernel<<<dim3(1920), dim3(256), 0, stream>>>(x, score, list, cnt, meta, Xc,
                                                      tokmap);
  stageA_kernel<<<dim3(16, 40, 1), dim3(256), 0, stream>>>(Xc, meta, Wgt, Wut, P);
  stageB_kernel<<<dim3(6, 40, 1), dim3(256), 0, stream>>>(P, meta, tokmap, Wdt, out);
}

// Round 12
// 172.342 us; speedup vs baseline: 1.0592x; 1.0037x over previous
//
#include <hip/hip_runtime.h>
#include <hip/hip_bf16.h>

// MoE MLP top-1 + shared expert. T=2048 H=768 I=2048 E=8, f32 in/out.
// R12: wconv = wave-per-row-segment phase-1 (1KB contiguous per instr),
//      [32k x 256n] blocks (2 dst chunks), kc-major block order (read spans),
//      dst layout (e,nt,kc) = stage-optimal (stages identical to R10).
//      Router fused, leading the grid.
// Chunk = 128 n x 32 k bf16 (4096 u16 = 8KB), in-chunk addr:
//   ((n>>4)&7)*512 + ((k>>3)&3)*128 + (n&15)*8 + (k&7)
// gll16 copies chunks linearly in the GEMMs; fragment reads linear-in-lane.

#define TT 2048
#define HH 768
#define II 2048
#define NE 8
#define RSLOTS 3072   // routed padded slots (24 tiles of 128)
#define RBLK 512      // router blocks (lead the fused grid)
#define WBLK 5184     // wconv blocks: 3456 gate/up + 1728 down (2 chunks each)
#define FLW 258       // wconv LDS row stride (f32): phase-2 2-lane/bank (free)

typedef unsigned short u16;
typedef unsigned int u32;
typedef short s16x8 __attribute__((ext_vector_type(8)));
typedef u16 u16x8 __attribute__((ext_vector_type(8)));
typedef float f32x4 __attribute__((ext_vector_type(4)));

__device__ __forceinline__ u16 f2bf(float f) {  // f32 -> bf16 RNE
  u32 u = __builtin_bit_cast(u32, f);
  return (u16)((u + 0x7FFFu + ((u >> 16) & 1u)) >> 16);
}

typedef __attribute__((address_space(3))) u32 lds_u32;
typedef const __attribute__((address_space(1))) u32 glb_u32;
__device__ __forceinline__ void gll16(const void* g, void* l) {
  // global src per-lane; LDS dest wave-uniform base + lane*16 (linear)
  __builtin_amdgcn_global_load_lds((glb_u32*)g,
                                   (lds_u32*)(u32)(unsigned long long)l, 16, 0, 0);
}

// ---------------- fused router + wconv ----------------
// blocks [0,RBLK): router (4 waves x 1 token each).
// blocks [RBLK,RBLK+WBLK): wconv, id = blockIdx.x - RBLK.
//   id<3456: gate/up. m=id/192 (e=m>>1, mat=m&1), rem=id%192, kc=rem>>3,
//            ntg=rem&7. src [32k x 256n] at (kc*32, ntg*256) of [768][2048].
//   id>=3456: down. id2=id-3456: e=id2/192, rem=id2%192, kc=rem/3, ntg=rem%3.
//            src [32k x 256n] of [2048][768].
// dst (e,nt,kc): Wg/Wu chunk ((e*16+nt)*24+kc); Wd ((e*6+nt)*64+kc); block
// writes nt = ntg*2, ntg*2+1. Consecutive blocks share kc -> contiguous reads.
__global__ __launch_bounds__(256) void wconv_router_kernel(
    const float* __restrict__ gate_w, const float* __restrict__ up_w,
    const float* __restrict__ down_w, const float* __restrict__ sh_gate,
    const float* __restrict__ sh_up, const float* __restrict__ sh_down,
    u16* __restrict__ Wgt, u16* __restrict__ Wut, u16* __restrict__ Wdt,
    const float* __restrict__ x, const float* __restrict__ rw,
    float* __restrict__ score, int* __restrict__ list, int* __restrict__ cnt,
    float* __restrict__ probsum) {
  __shared__ float fl[32 * FLW];  // 33 KB
  const int t = threadIdx.x;

  if (blockIdx.x < RBLK) {
    // ---- router: one wave per token ----
    const int tok = (int)((blockIdx.x * 256 + t) >> 6);
    const int lane = t & 63;
    if (tok >= TT) return;
    double acc[NE];
#pragma unroll
    for (int e = 0; e < NE; ++e) acc[e] = 0.0;
    const float* xr = x + (size_t)tok * HH;
    for (int h = lane; h < HH; h += 64) {
      const double xv = (double)xr[h];
#pragma unroll
      for (int e = 0; e < NE; ++e) acc[e] += xv * (double)rw[h * NE + e];
    }
#pragma unroll
    for (int off = 32; off > 0; off >>= 1) {
#pragma unroll
      for (int e = 0; e < NE; ++e) acc[e] += __shfl_xor(acc[e], off);
    }
    if (lane == 0) {
      int best = 0;
#pragma unroll
      for (int e = 1; e < NE; ++e)
        if (acc[e] > acc[best]) best = e;  // strict > == first-max (jnp.argmax)
      const float sc = 1.0f / (1.0f + __expf((float)(-acc[best])));
      score[tok] = sc;
      const int pos = atomicAdd(&cnt[best], 1);
      list[best * TT + pos] = tok;
      atomicAdd(&probsum[best], sc);
    }
    return;
  }

  // ---- wconv: one [32k x 256n] f32 tile -> two bf16 chunks ----
  const int id = blockIdx.x - RBLK;
  const float* src;
  u16 *dst0, *dst1;
  int N;
  if (id < 3456) {
    const int m = id / 192, rem = id % 192;
    const int kc = rem >> 3, ntg = rem & 7;
    const int e = m >> 1;
    const float* base = (m & 1) ? (e < 8 ? up_w + (size_t)e * HH * II : sh_up)
                                : (e < 8 ? gate_w + (size_t)e * HH * II : sh_gate);
    u16* wt = (m & 1) ? Wut : Wgt;
    N = II;
    src = base + (size_t)(kc * 32) * II + ntg * 256;
    dst0 = wt + ((size_t)(e * 16 + ntg * 2) * 24 + kc) * 4096;
    dst1 = wt + ((size_t)(e * 16 + ntg * 2 + 1) * 24 + kc) * 4096;
  } else {
    const int id2 = id - 3456;
    const int e = id2 / 192, rem = id2 % 192;
    const int kc = rem / 3, ntg = rem % 3;
    const float* base = (e < 8) ? down_w + (size_t)e * II * HH : sh_down;
    N = HH;
    src = base + (size_t)(kc * 32) * HH + ntg * 256;
    dst0 = Wdt + ((size_t)(e * 6 + ntg * 2) * 64 + kc) * 4096;
    dst1 = Wdt + ((size_t)(e * 6 + ntg * 2 + 1) * 64 + kc) * 4096;
  }
  // phase 1: wave per row-pass -> 1KB contiguous per instruction
  {
    const int wid = t >> 6, lane = t & 63;
#pragma unroll
    for (int q = 0; q < 8; ++q) {
      const int row = q * 4 + wid;
      const f32x4 v =
          *reinterpret_cast<const f32x4*>(src + (size_t)row * N + lane * 4);
      *reinterpret_cast<f32x4*>(&fl[row * FLW + lane * 4]) = v;
    }
  }
  __syncthreads();
  // phase 2: k-minor gather + convert; coalesced u16x8 stores (1KB/wave)
#pragma unroll
  for (int r = 0; r < 4; ++r) {
    const int o = r * 256 + t;  // 0..1023
    u16* dst = (o >> 9) ? dst1 : dst0;
    const int op = o & 511;
    const int fr = op & 15, fq = (op >> 4) & 3, nq = op >> 6;
    const int ncol = (o >> 9) * 128 + nq * 16 + fr;
    u16x8 w;
#pragma unroll
    for (int j = 0; j < 8; ++j) w[j] = f2bf(fl[(fq * 8 + j) * FLW + ncol]);
    *reinterpret_cast<u16x8*>(&dst[op * 8]) = w;
  }
}

// ---------------- plan: padded segments + tile->expert + loss ----------------
__global__ void plan_kernel(const int* __restrict__ cnt, const float* __restrict__ probsum,
                            int* __restrict__ meta, float* __restrict__ out) {
  if (threadIdx.x == 0) {
    int S = 0;
    for (int e = 0; e < NE; ++e) {
      meta[e] = S;
      const int pad = (cnt[e] + 127) & ~127;
      for (int t = S >> 7; t < (S + pad) >> 7; ++t) meta[16 + t] = e;
      S += pad;
    }
    meta[8] = S;
    for (int t = S >> 7; t < 24; ++t) meta[16 + t] = 0;
    float s = 0.0f;
    for (int e = 0; e < NE; ++e) s += (float)cnt[e] * probsum[e];
    out[(size_t)TT * HH] = s * (0.001f * (float)NE / ((float)TT * (float)TT));
  }
}

// ---------------- gather: x -> tiled bf16 Xc (+tokmap) ----------------
__global__ __launch_bounds__(256) void gather_kernel(
    const float* __restrict__ x, const float* __restrict__ score,
    const int* __restrict__ list, const int* __restrict__ cnt,
    const int* __restrict__ meta, u16* __restrict__ Xc, int* __restrict__ tokmap) {
  const int task = blockIdx.x * 4 + (threadIdx.x >> 6);
  const int lane = threadIdx.x & 63;
  const int pb = task / 24;  // 16-row block, 0..319
  const int c = task % 24;   // k chunk
  const int fq = lane >> 4, fr = lane & 15;
  const int p = pb * 16 + fr;
  int tok;
  float sc;
  if (p >= RSLOTS) {
    tok = p - RSLOTS;
    sc = 1.0f;
  } else {
    const int e = meta[16 + (p >> 7)];
    const int idx = p - meta[e];
    tok = (idx >= 0 && idx < cnt[e]) ? list[e * TT + idx] : -1;
    sc = (tok >= 0) ? score[tok] : 0.0f;
  }
  u16x8 w = {0, 0, 0, 0, 0, 0, 0, 0};
  if (tok >= 0) {
    const float* xp = x + (size_t)tok * HH + c * 32 + fq * 8;
    const f32x4 a = *reinterpret_cast<const f32x4*>(xp);
    const f32x4 b = *reinterpret_cast<const f32x4*>(xp + 4);
#pragma unroll
    for (int j = 0; j < 4; ++j) {
      w[j] = f2bf(a[j] * sc);
      w[j + 4] = f2bf(b[j] * sc);
    }
  }
  *reinterpret_cast<u16x8*>(&Xc[((size_t)(pb >> 3) * 24 + c) * 4096 + (pb & 7) * 512 +
                                lane * 8]) = w;
  if (c == 0 && fq == 0) tokmap[p] = tok;
}

// ---------------- stage A: P = silu(Xc Wg) * (Xc Wu) ----------------
// grid (16 nt, 40 mty): mty<24 routed (early-exit past Rp), >=24 shared (e=8).
__global__ __launch_bounds__(256, 3) void stageA_kernel(
    const u16* __restrict__ Xc, const int* __restrict__ meta,
    const u16* __restrict__ Wgt, const u16* __restrict__ Wut, u16* __restrict__ P) {
  const int mty = blockIdx.y, nt = blockIdx.x;
  int e;
  if (mty < 24) {
    if (mty * 128 >= meta[8]) return;
    e = meta[16 + mty];
  } else {
    e = 8;
  }
  const u16* wg = Wgt + (size_t)(e * 16 + nt) * 24 * 4096;
  const u16* wu = Wut + (size_t)(e * 16 + nt) * 24 * 4096;
  const u16* xa = Xc + (size_t)mty * 24 * 4096;

  __shared__ u16 As[2][4096], Bgs[2][4096], Bus[2][4096];

  const int tid = threadIdx.x, lane = tid & 63, wid = tid >> 6;
  const int fr = lane & 15, fq = lane >> 4;
  const int wm4 = (wid >> 1) * 4;  // row 16-block base
  const int wn4 = (wid & 1) * 4;   // col 16-block base
  const int wn = (wid & 1) * 64;
  const int ncol = nt * 128;
  const int so = wid * 1024 + lane * 8;  // gll global src offset (u16)
  const int sl = wid * 1024;             // gll LDS dst offset (u16), wave-uniform

  f32x4 accg[4][4], accu[4][4];
#pragma unroll
  for (int i = 0; i < 4; ++i)
#pragma unroll
    for (int j = 0; j < 4; ++j) {
      accg[i][j] = f32x4{0.f, 0.f, 0.f, 0.f};
      accu[i][j] = f32x4{0.f, 0.f, 0.f, 0.f};
    }

  // full chunk = 4096 u16; 4 waves x 2 gll16 x 512 u16 each
#define STAGE(c, buf)                                               \
  {                                                                 \
    gll16(xa + (size_t)(c) * 4096 + so, &As[buf][sl]);              \
    gll16(xa + (size_t)(c) * 4096 + so + 512, &As[buf][sl + 512]);  \
    gll16(wg + (size_t)(c) * 4096 + so, &Bgs[buf][sl]);             \
    gll16(wg + (size_t)(c) * 4096 + so + 512, &Bgs[buf][sl + 512]); \
    gll16(wu + (size_t)(c) * 4096 + so, &Bus[buf][sl]);             \
    gll16(wu + (size_t)(c) * 4096 + so + 512, &Bus[buf][sl + 512]); \
  }

  STAGE(0, 0)
  __syncthreads();
  int cur = 0;
  for (int c = 0; c < 24; ++c) {
    if (c < 23) STAGE(c + 1, cur ^ 1)
    s16x8 af[4], bg[4], bu[4];
#pragma unroll
    for (int i = 0; i < 4; ++i) {
      af[i] = *reinterpret_cast<const s16x8*>(&As[cur][(wm4 + i) * 512 + fq * 128 + fr * 8]);
      bg[i] = *reinterpret_cast<const s16x8*>(&Bgs[cur][(wn4 + i) * 512 + fq * 128 + fr * 8]);
      bu[i] = *reinterpret_cast<const s16x8*>(&Bus[cur][(wn4 + i) * 512 + fq * 128 + fr * 8]);
    }
#pragma unroll
    for (int j = 0; j < 4; ++j)
#pragma unroll
      for (int i = 0; i < 4; ++i) {
        accg[i][j] = __builtin_amdgcn_mfma_f32_16x16x32_bf16(af[i], bg[j], accg[i][j], 0, 0, 0);
        accu[i][j] = __builtin_amdgcn_mfma_f32_16x16x32_bf16(af[i], bu[j], accu[i][j], 0, 0, 0);
      }
    __syncthreads();
    cur ^= 1;
  }
#undef STAGE

  // epilogue: silu(g)*u -> P tiled bf16 (C/D: row=fq*4+reg, col=fr)
#pragma unroll
  for (int i = 0; i < 4; ++i)
#pragma unroll
    for (int cc = 0; cc < 4; ++cc) {
      const int rlo = fq * 4 + cc;  // row & 15 within 16-block (wm4+i)
#pragma unroll
      for (int j = 0; j < 4; ++j) {
        const int k = ncol + wn + j * 16 + fr;  // global i-col
        const float gv = accg[i][j][cc];
        const float val = (gv / (1.0f + __expf(-gv))) * accu[i][j][cc];
        P[((size_t)mty * 64 + (k >> 5)) * 4096 + (size_t)(wm4 + i) * 512 +
          ((k >> 3) & 3) * 128 + rlo * 8 + (k & 7)] = f2bf(val);
      }
    }
}

// ---------------- stage B: out += P Wd (atomicAdd, out pre-zeroed) ----------------
// grid (6 nt, 40 mty); each out element gets one shared + at most one routed add.
__global__ __launch_bounds__(256, 3) void stageB_kernel(
    const u16* __restrict__ P, const int* __restrict__ meta,
    const int* __restrict__ tokmap, const u16* __restrict__ Wdt,
    float* __restrict__ out) {
  const int mty = blockIdx.y, nt = blockIdx.x;
  int e;
  if (mty < 24) {
    if (mty * 128 >= meta[8]) return;
    e = meta[16 + mty];
  } else {
    e = 8;
  }
  const u16* wd = Wdt + (size_t)(e * 6 + nt) * 64 * 4096;
  const u16* pa = P + (size_t)mty * 64 * 4096;

  __shared__ u16 As[2][4096], Bs[2][4096];

  const int tid = threadIdx.x, lane = tid & 63, wid = tid >> 6;
  const int fr = lane & 15, fq = lane >> 4;
  const int wm4 = (wid >> 1) * 4;
  const int wn4 = (wid & 1) * 4;
  const int wm = (wid >> 1) * 64;
  const int wn = (wid & 1) * 64;
  const int ncol = nt * 128;
  const int so = wid * 1024 + lane * 8;
  const int sl = wid * 1024;

  f32x4 acc[4][4];
#pragma unroll
  for (int i = 0; i < 4; ++i)
#pragma unroll
    for (int j = 0; j < 4; ++j) acc[i][j] = f32x4{0.f, 0.f, 0.f, 0.f};

#define STAGEB(c, buf)                                              \
  {                                                                 \
    gll16(pa + (size_t)(c) * 4096 + so, &As[buf][sl]);              \
    gll16(pa + (size_t)(c) * 4096 + so + 512, &As[buf][sl + 512]);  \
    gll16(wd + (size_t)(c) * 4096 + so, &Bs[buf][sl]);              \
    gll16(wd + (size_t)(c) * 4096 + so + 512, &Bs[buf][sl + 512]);  \
  }

  STAGEB(0, 0)
  __syncthreads();
  int cur = 0;
  for (int c = 0; c < 64; ++c) {
    if (c < 63) STAGEB(c + 1, cur ^ 1)
    s16x8 af[4], bf[4];
#pragma unroll
    for (int i = 0; i < 4; ++i) {
      af[i] = *reinterpret_cast<const s16x8*>(&As[cur][(wm4 + i) * 512 + fq * 128 + fr * 8]);
      bf[i] = *reinterpret_cast<const s16x8*>(&Bs[cur][(wn4 + i) * 512 + fq * 128 + fr * 8]);
    }
#pragma unroll
    for (int j = 0; j < 4; ++j)
#pragma unroll
      for (int i = 0; i < 4; ++i)
        acc[i][j] = __builtin_amdgcn_mfma_f32_16x16x32_bf16(af[i], bf[j], acc[i][j], 0, 0, 0);
    __syncthreads();
    cur ^= 1;
  }
#undef STAGEB

#pragma unroll
  for (int i = 0; i < 4; ++i)
#pragma unroll
    for (int cc = 0; cc < 4; ++cc) {
      const int p = mty * 128 + wm + i * 16 + fq * 4 + cc;
      const int tok = tokmap[p];
      if (tok >= 0) {
#pragma unroll
        for (int j = 0; j < 4; ++j)
          atomicAdd(&out[(size_t)tok * HH + ncol + wn + j * 16 + fr], acc[i][j][cc]);
      }
    }
}

// ---------------- launcher ----------------
extern "C" void kernel_launch(void* const* d_in, const int* in_sizes, int n_in,
                              void* d_out, int out_size, void* d_ws, size_t ws_size,
                              hipStream_t stream) {
  (void)in_sizes; (void)n_in; (void)ws_size;
  const float* x = (const float*)d_in[0];
  const float* rw = (const float*)d_in[1];
  const float* gate_w = (const float*)d_in[2];
  const float* up_w = (const float*)d_in[3];
  const float* down_w = (const float*)d_in[4];
  const float* sh_gate = (const float*)d_in[5];
  const float* sh_up = (const float*)d_in[6];
  const float* sh_down = (const float*)d_in[7];
  float* out = (float*)d_out;

  char* ws = (char*)d_ws;
  size_t off = 0;
  u16* Xc = (u16*)(ws + off);  off += (size_t)(RSLOTS + TT) * HH * sizeof(u16);   // 7.9MB
  u16* P = (u16*)(ws + off);   off += (size_t)(RSLOTS + TT) * II * sizeof(u16);   // 21MB
  u16* Wgt = (u16*)(ws + off); off += (size_t)9 * 16 * 24 * 4096 * sizeof(u16);   // 28.3MB
  u16* Wut = (u16*)(ws + off); off += (size_t)9 * 16 * 24 * 4096 * sizeof(u16);   // 28.3MB
  u16* Wdt = (u16*)(ws + off); off += (size_t)9 * 6 * 64 * 4096 * sizeof(u16);    // 28.3MB
  float* score = (float*)(ws + off);   off += TT * sizeof(float);
  int* list = (int*)(ws + off);        off += (size_t)NE * TT * sizeof(int);
  int* cnt = (int*)(ws + off);         off += 16 * sizeof(int);
  float* probsum = (float*)(ws + off); off += 16 * sizeof(float);
  int* meta = (int*)(ws + off);        off += 64 * sizeof(int);
  int* tokmap = (int*)(ws + off);

  hipMemsetAsync(d_out, 0, (size_t)out_size * sizeof(float), stream);
  hipMemsetAsync(cnt, 0, 16 * sizeof(int) + 16 * sizeof(float), stream);
  wconv_router_kernel<<<dim3(RBLK + WBLK), dim3(256), 0, stream>>>(
      gate_w, up_w, down_w, sh_gate, sh_up, sh_down, Wgt, Wut, Wdt, x, rw, score,
      list, cnt, probsum);
  plan_kernel<<<dim3(1), dim3(64), 0, stream>>>(cnt, probsum, meta, out);
  gather_kernel<<<dim3(1920), dim3(256), 0, stream>>>(x, score, list, cnt, meta, Xc,
                                                      tokmap);
  stageA_kernel<<<dim3(16, 40, 1), dim3(256), 0, stream>>>(Xc, meta, Wgt, Wut, P);
  stageB_kernel<<<dim3(6, 40, 1), dim3(256), 0, stream>>>(P, meta, tokmap, Wdt, out);
}

// Round 13
// 164.713 us; speedup vs baseline: 1.1083x; 1.0463x over previous
//
#include <hip/hip_runtime.h>
#include <hip/hip_bf16.h>

// MoE MLP top-1 + shared expert. T=2048 H=768 I=2048 E=8, f32 in/out.
// R13: schedule overlap. K1 = router + gate/up wconv (R5 body, kc-major).
//      K2 = stageA + down-wconv fused in one grid (down rides under MFMA).
//      K3 = stageB. Layouts all (e,nt,kc) = stage-optimal (R10/R12 strides).
// Chunk = 128 n x 32 k bf16 (4096 u16 = 8KB), in-chunk addr:
//   ((n>>4)&7)*512 + ((k>>3)&3)*128 + (n&15)*8 + (k&7)
// gll16 copies chunks linearly in the GEMMs; fragment reads linear-in-lane.

#define TT 2048
#define HH 768
#define II 2048
#define NE 8
#define RSLOTS 3072   // routed padded slots (24 tiles of 128)
#define LDSW 138      // wconv LDS row stride (u16)
#define RBLK 512      // router blocks (lead K1's grid)
#define GUCH 6912     // gate/up chunks (9 x {g,u} x 24 kc x 16 nt)
#define SABLK 640     // stageA blocks (16 nt x 40 mty)
#define DCH 3456      // down chunks (9 x 64 kc x 6 nt)

typedef unsigned short u16;
typedef unsigned int u32;
typedef short s16x8 __attribute__((ext_vector_type(8)));
typedef u16 u16x8 __attribute__((ext_vector_type(8)));
typedef float f32x4 __attribute__((ext_vector_type(4)));

__device__ __forceinline__ u16 f2bf(float f) {  // f32 -> bf16 RNE
  u32 u = __builtin_bit_cast(u32, f);
  return (u16)((u + 0x7FFFu + ((u >> 16) & 1u)) >> 16);
}

typedef __attribute__((address_space(3))) u32 lds_u32;
typedef const __attribute__((address_space(1))) u32 glb_u32;
__device__ __forceinline__ void gll16(const void* g, void* l) {
  // global src per-lane; LDS dest wave-uniform base + lane*16 (linear)
  __builtin_amdgcn_global_load_lds((glb_u32*)g,
                                   (lds_u32*)(u32)(unsigned long long)l, 16, 0, 0);
}

// R5 one-shot conv body: [32k x 128n] f32 (row stride N) -> one tiled chunk.
__device__ __forceinline__ void conv_chunk(const float* src, int N, int k0, int n0,
                                           u16* dst, u16* lds, int t) {
  // phase 1: coalesced f32x4 reads along n; bf16 rows into LDS
  {
    const int k = t >> 3;         // 0..31
    const int nb = (t & 7) * 16;  // 16 consecutive n per thread
    const float* rp = src + (size_t)(k0 + k) * N + n0 + nb;
    const f32x4 a0 = *reinterpret_cast<const f32x4*>(rp);
    const f32x4 a1 = *reinterpret_cast<const f32x4*>(rp + 4);
    const f32x4 a2 = *reinterpret_cast<const f32x4*>(rp + 8);
    const f32x4 a3 = *reinterpret_cast<const f32x4*>(rp + 12);
    u16x8 w0, w1;
#pragma unroll
    for (int j = 0; j < 4; ++j) {
      w0[j] = f2bf(a0[j]); w0[j + 4] = f2bf(a1[j]);
      w1[j] = f2bf(a2[j]); w1[j + 4] = f2bf(a3[j]);
    }
    *reinterpret_cast<u16x8*>(&lds[k * LDSW + nb]) = w0;
    *reinterpret_cast<u16x8*>(&lds[k * LDSW + nb + 8]) = w1;
  }
  __syncthreads();
  // phase 2: k-minor gather from LDS, coalesced u16x8 stores
#pragma unroll
  for (int r = 0; r < 2; ++r) {
    const int o = t + r * 256;  // 0..511
    const int fr = o & 15, fq = (o >> 4) & 3, nq = o >> 6;
    u16x8 w;
#pragma unroll
    for (int j = 0; j < 8; ++j) w[j] = lds[(fq * 8 + j) * LDSW + nq * 16 + fr];
    *reinterpret_cast<u16x8*>(&dst[o * 8]) = w;
  }
}

// ---------------- K1: router + gate/up conversion ----------------
// blocks [0,RBLK): router (4 waves x 1 token). blocks [RBLK,RBLK+GUCH):
// gu chunks, id: m=id/384 (e=m>>1, mat=m&1), r=id%384, kc=r>>4, nt=r&15
// (kc-major -> concurrent blocks read contiguous row spans).
// dst (e,nt,kc): chunk ((e*16+nt)*24+kc).
__global__ __launch_bounds__(256) void guconv_router_kernel(
    const float* __restrict__ gate_w, const float* __restrict__ up_w,
    const float* __restrict__ sh_gate, const float* __restrict__ sh_up,
    u16* __restrict__ Wgt, u16* __restrict__ Wut,
    const float* __restrict__ x, const float* __restrict__ rw,
    float* __restrict__ score, int* __restrict__ list, int* __restrict__ cnt,
    float* __restrict__ probsum) {
  __shared__ u16 lds[32 * LDSW];  // 8.8 KB
  const int t = threadIdx.x;

  if (blockIdx.x < RBLK) {
    // ---- router: one wave per token ----
    const int tok = (int)((blockIdx.x * 256 + t) >> 6);
    const int lane = t & 63;
    if (tok >= TT) return;
    double acc[NE];
#pragma unroll
    for (int e = 0; e < NE; ++e) acc[e] = 0.0;
    const float* xr = x + (size_t)tok * HH;
    for (int h = lane; h < HH; h += 64) {
      const double xv = (double)xr[h];
#pragma unroll
      for (int e = 0; e < NE; ++e) acc[e] += xv * (double)rw[h * NE + e];
    }
#pragma unroll
    for (int off = 32; off > 0; off >>= 1) {
#pragma unroll
      for (int e = 0; e < NE; ++e) acc[e] += __shfl_xor(acc[e], off);
    }
    if (lane == 0) {
      int best = 0;
#pragma unroll
      for (int e = 1; e < NE; ++e)
        if (acc[e] > acc[best]) best = e;  // strict > == first-max (jnp.argmax)
      const float sc = 1.0f / (1.0f + __expf((float)(-acc[best])));
      score[tok] = sc;
      const int pos = atomicAdd(&cnt[best], 1);
      list[best * TT + pos] = tok;
      atomicAdd(&probsum[best], sc);
    }
    return;
  }

  const int id = blockIdx.x - RBLK;  // [0, GUCH)
  const int m = id / 384, r = id % 384;
  const int e = m >> 1;
  const int kc = r >> 4, nt = r & 15;  // kc-major, nt-minor
  const float* src = (m & 1) ? (e < 8 ? up_w + (size_t)e * HH * II : sh_up)
                             : (e < 8 ? gate_w + (size_t)e * HH * II : sh_gate);
  u16* dst = ((m & 1) ? Wut : Wgt) + ((size_t)(e * 16 + nt) * 24 + kc) * 4096;
  conv_chunk(src, II, kc * 32, nt * 128, dst, lds, t);
}

// ---------------- plan: padded segments + tile->expert + loss ----------------
__global__ void plan_kernel(const int* __restrict__ cnt, const float* __restrict__ probsum,
                            int* __restrict__ meta, float* __restrict__ out) {
  if (threadIdx.x == 0) {
    int S = 0;
    for (int e = 0; e < NE; ++e) {
      meta[e] = S;
      const int pad = (cnt[e] + 127) & ~127;
      for (int t = S >> 7; t < (S + pad) >> 7; ++t) meta[16 + t] = e;
      S += pad;
    }
    meta[8] = S;
    for (int t = S >> 7; t < 24; ++t) meta[16 + t] = 0;
    float s = 0.0f;
    for (int e = 0; e < NE; ++e) s += (float)cnt[e] * probsum[e];
    out[(size_t)TT * HH] = s * (0.001f * (float)NE / ((float)TT * (float)TT));
  }
}

// ---------------- gather: x -> tiled bf16 Xc (+tokmap) ----------------
__global__ __launch_bounds__(256) void gather_kernel(
    const float* __restrict__ x, const float* __restrict__ score,
    const int* __restrict__ list, const int* __restrict__ cnt,
    const int* __restrict__ meta, u16* __restrict__ Xc, int* __restrict__ tokmap) {
  const int task = blockIdx.x * 4 + (threadIdx.x >> 6);
  const int lane = threadIdx.x & 63;
  const int pb = task / 24;  // 16-row block, 0..319
  const int c = task % 24;   // k chunk
  const int fq = lane >> 4, fr = lane & 15;
  const int p = pb * 16 + fr;
  int tok;
  float sc;
  if (p >= RSLOTS) {
    tok = p - RSLOTS;
    sc = 1.0f;
  } else {
    const int e = meta[16 + (p >> 7)];
    const int idx = p - meta[e];
    tok = (idx >= 0 && idx < cnt[e]) ? list[e * TT + idx] : -1;
    sc = (tok >= 0) ? score[tok] : 0.0f;
  }
  u16x8 w = {0, 0, 0, 0, 0, 0, 0, 0};
  if (tok >= 0) {
    const float* xp = x + (size_t)tok * HH + c * 32 + fq * 8;
    const f32x4 a = *reinterpret_cast<const f32x4*>(xp);
    const f32x4 b = *reinterpret_cast<const f32x4*>(xp + 4);
#pragma unroll
    for (int j = 0; j < 4; ++j) {
      w[j] = f2bf(a[j] * sc);
      w[j + 4] = f2bf(b[j] * sc);
    }
  }
  *reinterpret_cast<u16x8*>(&Xc[((size_t)(pb >> 3) * 24 + c) * 4096 + (pb & 7) * 512 +
                                lane * 8]) = w;
  if (c == 0 && fq == 0) tokmap[p] = tok;
}

// ---------------- K2: stageA + down conversion fused ----------------
// blocks [0,SABLK): stageA (nt=b&15, mty=b>>4; mty<24 routed, >=24 shared).
// blocks [SABLK,SABLK+DCH): down chunks, id: e=id/384, r=id%384, kc=r/6, nt=r%6
// (kc-major). dst (e,nt,kc): chunk ((e*6+nt)*64+kc). Wdt consumed by stageB.
__global__ __launch_bounds__(256, 3) void stageA_dconv_kernel(
    const u16* __restrict__ Xc, const int* __restrict__ meta,
    const u16* __restrict__ Wgt, const u16* __restrict__ Wut, u16* __restrict__ P,
    const float* __restrict__ down_w, const float* __restrict__ sh_down,
    u16* __restrict__ Wdt) {
  __shared__ char smem[49152];  // stageA: 48 KB; down conv: first 8.8 KB
  const int tid = threadIdx.x;

  if (blockIdx.x >= SABLK) {
    // ---- down conversion (R5 body) ----
    const int id = blockIdx.x - SABLK;  // [0, DCH)
    const int e = id / 384, r = id % 384;
    const int kc = r / 6, nt = r % 6;  // kc-major, nt-minor
    const float* src = (e < 8) ? down_w + (size_t)e * II * HH : sh_down;
    u16* dst = Wdt + ((size_t)(e * 6 + nt) * 64 + kc) * 4096;
    conv_chunk(src, HH, kc * 32, nt * 128, dst, (u16*)smem, tid);
    return;
  }

  // ---- stageA: P = silu(Xc Wg) * (Xc Wu) ----
  const int nt = blockIdx.x & 15, mty = blockIdx.x >> 4;
  int e;
  if (mty < 24) {
    if (mty * 128 >= meta[8]) return;
    e = meta[16 + mty];
  } else {
    e = 8;
  }
  const u16* wg = Wgt + (size_t)(e * 16 + nt) * 24 * 4096;
  const u16* wu = Wut + (size_t)(e * 16 + nt) * 24 * 4096;
  const u16* xa = Xc + (size_t)mty * 24 * 4096;

  u16(*As)[4096] = (u16(*)[4096])smem;
  u16(*Bgs)[4096] = (u16(*)[4096])(smem + 16384);
  u16(*Bus)[4096] = (u16(*)[4096])(smem + 32768);

  const int lane = tid & 63, wid = tid >> 6;
  const int fr = lane & 15, fq = lane >> 4;
  const int wm4 = (wid >> 1) * 4;  // row 16-block base
  const int wn4 = (wid & 1) * 4;   // col 16-block base
  const int wn = (wid & 1) * 64;
  const int ncol = nt * 128;
  const int so = wid * 1024 + lane * 8;  // gll global src offset (u16)
  const int sl = wid * 1024;             // gll LDS dst offset (u16), wave-uniform

  f32x4 accg[4][4], accu[4][4];
#pragma unroll
  for (int i = 0; i < 4; ++i)
#pragma unroll
    for (int j = 0; j < 4; ++j) {
      accg[i][j] = f32x4{0.f, 0.f, 0.f, 0.f};
      accu[i][j] = f32x4{0.f, 0.f, 0.f, 0.f};
    }

  // full chunk = 4096 u16; 4 waves x 2 gll16 x 512 u16 each
#define STAGE(c, buf)                                               \
  {                                                                 \
    gll16(xa + (size_t)(c) * 4096 + so, &As[buf][sl]);              \
    gll16(xa + (size_t)(c) * 4096 + so + 512, &As[buf][sl + 512]);  \
    gll16(wg + (size_t)(c) * 4096 + so, &Bgs[buf][sl]);             \
    gll16(wg + (size_t)(c) * 4096 + so + 512, &Bgs[buf][sl + 512]); \
    gll16(wu + (size_t)(c) * 4096 + so, &Bus[buf][sl]);             \
    gll16(wu + (size_t)(c) * 4096 + so + 512, &Bus[buf][sl + 512]); \
  }

  STAGE(0, 0)
  __syncthreads();
  int cur = 0;
  for (int c = 0; c < 24; ++c) {
    if (c < 23) STAGE(c + 1, cur ^ 1)
    s16x8 af[4], bg[4], bu[4];
#pragma unroll
    for (int i = 0; i < 4; ++i) {
      af[i] = *reinterpret_cast<const s16x8*>(&As[cur][(wm4 + i) * 512 + fq * 128 + fr * 8]);
      bg[i] = *reinterpret_cast<const s16x8*>(&Bgs[cur][(wn4 + i) * 512 + fq * 128 + fr * 8]);
      bu[i] = *reinterpret_cast<const s16x8*>(&Bus[cur][(wn4 + i) * 512 + fq * 128 + fr * 8]);
    }
#pragma unroll
    for (int j = 0; j < 4; ++j)
#pragma unroll
      for (int i = 0; i < 4; ++i) {
        accg[i][j] = __builtin_amdgcn_mfma_f32_16x16x32_bf16(af[i], bg[j], accg[i][j], 0, 0, 0);
        accu[i][j] = __builtin_amdgcn_mfma_f32_16x16x32_bf16(af[i], bu[j], accu[i][j], 0, 0, 0);
      }
    __syncthreads();
    cur ^= 1;
  }
#undef STAGE

  // epilogue: silu(g)*u -> P tiled bf16 (C/D: row=fq*4+reg, col=fr)
#pragma unroll
  for (int i = 0; i < 4; ++i)
#pragma unroll
    for (int cc = 0; cc < 4; ++cc) {
      const int rlo = fq * 4 + cc;  // row & 15 within 16-block (wm4+i)
#pragma unroll
      for (int j = 0; j < 4; ++j) {
        const int k = ncol + wn + j * 16 + fr;  // global i-col
        const float gv = accg[i][j][cc];
        const float val = (gv / (1.0f + __expf(-gv))) * accu[i][j][cc];
        P[((size_t)mty * 64 + (k >> 5)) * 4096 + (size_t)(wm4 + i) * 512 +
          ((k >> 3) & 3) * 128 + rlo * 8 + (k & 7)] = f2bf(val);
      }
    }
}

// ---------------- stage B: out += P Wd (atomicAdd, out pre-zeroed) ----------------
// grid (6 nt, 40 mty); each out element gets one shared + at most one routed add.
__global__ __launch_bounds__(256, 3) void stageB_kernel(
    const u16* __restrict__ P, const int* __restrict__ meta,
    const int* __restrict__ tokmap, const u16* __restrict__ Wdt,
    float* __restrict__ out) {
  const int mty = blockIdx.y, nt = blockIdx.x;
  int e;
  if (mty < 24) {
    if (mty * 128 >= meta[8]) return;
    e = meta[16 + mty];
  } else {
    e = 8;
  }
  const u16* wd = Wdt + (size_t)(e * 6 + nt) * 64 * 4096;
  const u16* pa = P + (size_t)mty * 64 * 4096;

  __shared__ u16 As[2][4096], Bs[2][4096];

  const int tid = threadIdx.x, lane = tid & 63, wid = tid >> 6;
  const int fr = lane & 15, fq = lane >> 4;
  const int wm4 = (wid >> 1) * 4;
  const int wn4 = (wid & 1) * 4;
  const int wm = (wid >> 1) * 64;
  const int wn = (wid & 1) * 64;
  const int ncol = nt * 128;
  const int so = wid * 1024 + lane * 8;
  const int sl = wid * 1024;

  f32x4 acc[4][4];
#pragma unroll
  for (int i = 0; i < 4; ++i)
#pragma unroll
    for (int j = 0; j < 4; ++j) acc[i][j] = f32x4{0.f, 0.f, 0.f, 0.f};

#define STAGEB(c, buf)                                              \
  {                                                                 \
    gll16(pa + (size_t)(c) * 4096 + so, &As[buf][sl]);              \
    gll16(pa + (size_t)(c) * 4096 + so + 512, &As[buf][sl + 512]);  \
    gll16(wd + (size_t)(c) * 4096 + so, &Bs[buf][sl]);              \
    gll16(wd + (size_t)(c) * 4096 + so + 512, &Bs[buf][sl + 512]);  \
  }

  STAGEB(0, 0)
  __syncthreads();
  int cur = 0;
  for (int c = 0; c < 64; ++c) {
    if (c < 63) STAGEB(c + 1, cur ^ 1)
    s16x8 af[4], bf[4];
#pragma unroll
    for (int i = 0; i < 4; ++i) {
      af[i] = *reinterpret_cast<const s16x8*>(&As[cur][(wm4 + i) * 512 + fq * 128 + fr * 8]);
      bf[i] = *reinterpret_cast<const s16x8*>(&Bs[cur][(wn4 + i) * 512 + fq * 128 + fr * 8]);
    }
#pragma unroll
    for (int j = 0; j < 4; ++j)
#pragma unroll
      for (int i = 0; i < 4; ++i)
        acc[i][j] = __builtin_amdgcn_mfma_f32_16x16x32_bf16(af[i], bf[j], acc[i][j], 0, 0, 0);
    __syncthreads();
    cur ^= 1;
  }
#undef STAGEB

#pragma unroll
  for (int i = 0; i < 4; ++i)
#pragma unroll
    for (int cc = 0; cc < 4; ++cc) {
      const int p = mty * 128 + wm + i * 16 + fq * 4 + cc;
      const int tok = tokmap[p];
      if (tok >= 0) {
#pragma unroll
        for (int j = 0; j < 4; ++j)
          atomicAdd(&out[(size_t)tok * HH + ncol + wn + j * 16 + fr], acc[i][j][cc]);
      }
    }
}

// ---------------- launcher ----------------
extern "C" void kernel_launch(void* const* d_in, const int* in_sizes, int n_in,
                              void* d_out, int out_size, void* d_ws, size_t ws_size,
                              hipStream_t stream) {
  (void)in_sizes; (void)n_in; (void)ws_size;
  const float* x = (const float*)d_in[0];
  const float* rw = (const float*)d_in[1];
  const float* gate_w = (const float*)d_in[2];
  const float* up_w = (const float*)d_in[3];
  const float* down_w = (const float*)d_in[4];
  const float* sh_gate = (const float*)d_in[5];
  const float* sh_up = (const float*)d_in[6];
  const float* sh_down = (const float*)d_in[7];
  float* out = (float*)d_out;

  char* ws = (char*)d_ws;
  size_t off = 0;
  u16* Xc = (u16*)(ws + off);  off += (size_t)(RSLOTS + TT) * HH * sizeof(u16);   // 7.9MB
  u16* P = (u16*)(ws + off);   off += (size_t)(RSLOTS + TT) * II * sizeof(u16);   // 21MB
  u16* Wgt = (u16*)(ws + off); off += (size_t)9 * 16 * 24 * 4096 * sizeof(u16);   // 28.3MB
  u16* Wut = (u16*)(ws + off); off += (size_t)9 * 16 * 24 * 4096 * sizeof(u16);   // 28.3MB
  u16* Wdt = (u16*)(ws + off); off += (size_t)9 * 6 * 64 * 4096 * sizeof(u16);    // 28.3MB
  float* score = (float*)(ws + off);   off += TT * sizeof(float);
  int* list = (int*)(ws + off);        off += (size_t)NE * TT * sizeof(int);
  int* cnt = (int*)(ws + off);         off += 16 * sizeof(int);
  float* probsum = (float*)(ws + off); off += 16 * sizeof(float);
  int* meta = (int*)(ws + off);        off += 64 * sizeof(int);
  int* tokmap = (int*)(ws + off);

  hipMemsetAsync(d_out, 0, (size_t)out_size * sizeof(float), stream);
  hipMemsetAsync(cnt, 0, 16 * sizeof(int) + 16 * sizeof(float), stream);
  guconv_router_kernel<<<dim3(RBLK + GUCH), dim3(256), 0, stream>>>(
      gate_w, up_w, sh_gate, sh_up, Wgt, Wut, x, rw, score, list, cnt, probsum);
  plan_kernel<<<dim3(1), dim3(64), 0, stream>>>(cnt, probsum, meta, out);
  gather_kernel<<<dim3(1920), dim3(256), 0, stream>>>(x, score, list, cnt, meta, Xc,
                                                      tokmap);
  stageA_dconv_kernel<<<dim3(SABLK + DCH), dim3(256), 0, stream>>>(
      Xc, meta, Wgt, Wut, P, down_w, sh_down, Wdt);
  stageB_kernel<<<dim3(6, 40, 1), dim3(256), 0, stream>>>(P, meta, tokmap, Wdt, out);
}